// Round 2
// baseline (1495.006 us; speedup 1.0000x reference)
//
#include <hip/hip_runtime.h>
#include <hip/hip_bf16.h>

typedef __hip_bfloat16 bf16;
typedef __attribute__((ext_vector_type(8))) short short8;
typedef __attribute__((ext_vector_type(4))) float f32x4;

#define NB 4
#define NT 1024
#define NE 2048
#define NH 32
#define ND 64
#define NBH (NB*NH)

__device__ __forceinline__ short bf16bits(float x) {
    bf16 h = __float2bfloat16(x);
    return *reinterpret_cast<short*>(&h);
}
__device__ __forceinline__ float bitsbf16(short s) {
    bf16 h = *reinterpret_cast<bf16*>(&s);
    return __bfloat162float(h);
}

// Load 8 consecutive elements as a bf16 MFMA fragment from fp32 or bf16 storage.
__device__ __forceinline__ short8 ldfrag(const void* base, size_t off, bool f32) {
    if (f32) {
        const float* p = (const float*)base + off;
        f32x4 a = *(const f32x4*)p;
        f32x4 b = *(const f32x4*)(p + 4);
        short8 r;
        r[0] = bf16bits(a[0]); r[1] = bf16bits(a[1]);
        r[2] = bf16bits(a[2]); r[3] = bf16bits(a[3]);
        r[4] = bf16bits(b[0]); r[5] = bf16bits(b[1]);
        r[6] = bf16bits(b[2]); r[7] = bf16bits(b[3]);
        return r;
    }
    return *(const short8*)((const bf16*)base + off);
}

// Storage-dtype probe: interpret first 512 halfwords of wq as bf16. fp32 storage
// puts pseudo-random mantissa halves at even indices -> some exponent >= 0x88
// (|x|>=512 or inf/nan) with overwhelming probability. Real bf16 weights
// (~N(0,0.02^2)) never exceed |x|~0.2. flag=1 -> inputs are fp32.
__global__ void detect_dtype(const unsigned short* __restrict__ w, int* __restrict__ flag) {
    int l = threadIdx.x;
    int big = 0;
    for (int i = l; i < 512; i += 64) {
        unsigned e = (w[i] >> 7) & 0xFFu;
        if (e >= 0x88u) big = 1;
    }
    unsigned long long m = __ballot(big != 0);
    if (l == 0) *flag = (m != 0ULL) ? 1 : 0;
}

// C[m,n] = (sum_k A[m,k]*W[n,k] + bias[n]) * scale   (K = N = NE)
// MODE 0: out row-major [M,N], dtype per flag (fp32 or bf16)  -> d_out
// MODE 1: out bf16 [B,H,T,D]
// MODE 2: out bf16 [B,H,D,T]   (direct-transposed V)
// A_DYN: A dtype per flag (inputs); false -> A is always bf16 (our workspace).
template<bool A_DYN, int MODE>
__global__ __launch_bounds__(256) void gemm_bt(
    const void* __restrict__ A, const void* __restrict__ W,
    const void* __restrict__ bias, float scale, void* __restrict__ out,
    const int* __restrict__ flagp)
{
    const int K = NE, N = NE;
    const bool f32 = (*flagp != 0);
    int tid = threadIdx.x;
    int w = tid >> 6, l = tid & 63;
    int lr = l & 15, quad = l >> 4;
    int mBase = blockIdx.y * 128 + (w >> 1) * 64;
    int nBase = blockIdx.x * 128 + (w & 1) * 64;

    f32x4 acc[4][4] = {};
    size_t aoff = (size_t)(mBase + lr) * K + quad * 8;
    size_t woff = (size_t)(nBase + lr) * K + quad * 8;

    for (int k0 = 0; k0 < K; k0 += 32) {
        short8 af[4], bfr[4];
        for (int i = 0; i < 4; i++) {
            size_t o = aoff + (size_t)i * 16 * K + k0;
            af[i] = A_DYN ? ldfrag(A, o, f32)
                          : *(const short8*)((const bf16*)A + o);
        }
        for (int j = 0; j < 4; j++)
            bfr[j] = ldfrag(W, woff + (size_t)j * 16 * K + k0, f32);
        for (int i = 0; i < 4; i++)
            for (int j = 0; j < 4; j++)
                acc[i][j] = __builtin_amdgcn_mfma_f32_16x16x32_bf16(
                    af[i], bfr[j], acc[i][j], 0, 0, 0);
    }

    for (int i = 0; i < 4; i++) {
        for (int j = 0; j < 4; j++) {
            int n = nBase + j * 16 + lr;
            float bv = f32 ? ((const float*)bias)[n]
                           : bitsbf16(((const short*)bias)[n]);
            for (int r = 0; r < 4; r++) {
                int m = mBase + i * 16 + quad * 4 + r;
                float v = (acc[i][j][r] + bv) * scale;
                if (MODE == 0) {
                    if (f32) ((float*)out)[(size_t)m * N + n] = v;
                    else     ((bf16*)out)[(size_t)m * N + n] = (bf16)v;
                } else {
                    int b = m >> 10, t = m & (NT - 1);
                    int h = n >> 6, d = n & (ND - 1);
                    if (MODE == 1)
                        ((bf16*)out)[(((size_t)(b * NH + h)) * NT + t) * ND + d] = (bf16)v;
                    else
                        ((bf16*)out)[(((size_t)(b * NH + h)) * ND + d) * NT + t] = (bf16)v;
                }
            }
        }
    }
}

// sK[bh,d] = max(1e-5, max_t |K[bh,t,d]|);  K layout [BH,T,D]
__global__ __launch_bounds__(256) void stats_k(
    const bf16* __restrict__ K, float* __restrict__ sK)
{
    int bh = blockIdx.x;
    int d = threadIdx.x & 63, tg = threadIdx.x >> 6;
    const bf16* Kp = K + (size_t)bh * NT * ND;
    float kabs = 0.f;
    for (int t = tg; t < NT; t += 4)
        kabs = fmaxf(kabs, fabsf((float)Kp[t * ND + d]));
    __shared__ float sh[4][64];
    sh[tg][d] = kabs;
    __syncthreads();
    if (threadIdx.x < 64) {
        kabs = fmaxf(fmaxf(sh[0][d], sh[1][d]), fmaxf(sh[2][d], sh[3][d]));
        sK[bh * 64 + d] = fmaxf(kabs, 1e-5f);
    }
}

// Per-channel (over tokens) scale/zero for V; Vt layout [BH,D,T]
__global__ __launch_bounds__(256) void stats_v(
    const bf16* __restrict__ Vt, float* __restrict__ vScale, float* __restrict__ vZero)
{
    int bh = blockIdx.x;
    int c = threadIdx.x >> 2;      // channel 0..63
    int seg = threadIdx.x & 3;     // quarter of the token row
    const bf16* row = Vt + ((size_t)bh * ND + c) * NT + seg * 256;
    float vmax = 0.f, vmin = 0.f;  // seeded with 0: matches jnp max(.,0)/min(.,0)
    for (int i = 0; i < 256; i += 8) {
        short8 v8 = *(const short8*)(row + i);
        for (int j = 0; j < 8; j++) {
            float f = bitsbf16(v8[j]);
            vmax = fmaxf(vmax, f);
            vmin = fminf(vmin, f);
        }
    }
    vmax = fmaxf(vmax, __shfl_xor(vmax, 1));
    vmax = fmaxf(vmax, __shfl_xor(vmax, 2));
    vmin = fminf(vmin, __shfl_xor(vmin, 1));
    vmin = fminf(vmin, __shfl_xor(vmin, 2));
    if (seg == 0) {
        float sc = (vmax - vmin) * (1.f / 255.f);
        if (sc <= 0.f) sc = 1.f;
        vScale[bh * 64 + c] = sc;
        vZero[bh * 64 + c] = rintf(-vmin / sc);
    }
}

// Per-token (over d=64) fake-quant of Q; smooth+quant of K. In place.
__global__ __launch_bounds__(256) void quant_qk(
    bf16* __restrict__ Q, bf16* __restrict__ K, const float* __restrict__ sK)
{
    int bh = blockIdx.y;
    int t = blockIdx.x * 4 + (threadIdx.x >> 6);
    int l = threadIdx.x & 63;
    size_t idx = ((size_t)bh * NT + t) * ND + l;
    {
        float x = (float)Q[idx];
        float xmax = fmaxf(x, 0.f), xmin = fminf(x, 0.f);
        for (int off = 1; off < 64; off <<= 1) {
            xmax = fmaxf(xmax, __shfl_xor(xmax, off));
            xmin = fminf(xmin, __shfl_xor(xmin, off));
        }
        float sc = (xmax - xmin) * (1.f / 255.f);
        if (sc <= 0.f) sc = 1.f;
        float z = rintf(-xmin / sc);
        float q = fminf(fmaxf(rintf(x / sc) + z, 0.f), 255.f);
        Q[idx] = (bf16)(sc * (q - z));
    }
    {
        float s = sK[bh * 64 + l];
        float x = (float)K[idx] / s;
        float xmax = fmaxf(x, 0.f), xmin = fminf(x, 0.f);
        for (int off = 1; off < 64; off <<= 1) {
            xmax = fmaxf(xmax, __shfl_xor(xmax, off));
            xmin = fminf(xmin, __shfl_xor(xmin, off));
        }
        float sc = (xmax - xmin) * (1.f / 255.f);
        if (sc <= 0.f) sc = 1.f;
        float z = rintf(-xmin / sc);
        float q = fminf(fmaxf(rintf(x / sc) + z, 0.f), 255.f);
        K[idx] = (bf16)(s * (sc * (q - z)));
    }
}

// V fake-quant along tokens, in place on Vt [BH,D,T].
__global__ __launch_bounds__(256) void quant_v(
    bf16* __restrict__ Vt,
    const float* __restrict__ vScale, const float* __restrict__ vZero)
{
    int bh = blockIdx.y, d = blockIdx.x;
    float sc = vScale[bh * 64 + d], z = vZero[bh * 64 + d];
    bf16* row = Vt + ((size_t)bh * ND + d) * NT;
    for (int t = threadIdx.x; t < NT; t += 256) {
        float v = (float)row[t];
        float q = fminf(fmaxf(rintf(v / sc) + z, 0.f), 255.f);
        row[t] = (bf16)(sc * (q - z));
    }
}

// Flash-style causal attention. Q,K: [BH,T,D] bf16 (quantized); Vt: [BH,D,T].
// O: [B,T,E] bf16. Block = 64 Q rows (4 waves x 16), K tiles of 64.
__global__ __launch_bounds__(256) void attn(
    const bf16* __restrict__ Q, const bf16* __restrict__ K,
    const bf16* __restrict__ Vt, bf16* __restrict__ O)
{
    int bh = blockIdx.y;
    int b = bh >> 5, h = bh & 31;
    int qBase = blockIdx.x * 64;
    int w = threadIdx.x >> 6, l = threadIdx.x & 63;
    int lr = l & 15, quad = l >> 4;
    int qRow = qBase + w * 16;

    __shared__ __align__(16) bf16 Psh[4][16][64];

    const bf16* Qp = Q + ((size_t)bh * NT + qRow + lr) * ND + quad * 8;
    short8 qf0 = *(const short8*)(Qp);
    short8 qf1 = *(const short8*)(Qp + 32);

    f32x4 o[4] = {};
    float m_i[4], l_i[4];
    for (int r = 0; r < 4; r++) { m_i[r] = -1e30f; l_i[r] = 0.f; }

    int nkt = (qBase >> 6) + 1;
    const bf16* Kbase = K + (size_t)bh * NT * ND;
    const bf16* Vbase = Vt + (size_t)bh * ND * NT;

    for (int kt = 0; kt < nkt; kt++) {
        int kc0 = kt * 64;
        f32x4 s[4] = {};
        for (int nb = 0; nb < 4; nb++) {
            const bf16* Kp = Kbase + (size_t)(kc0 + nb * 16 + lr) * ND + quad * 8;
            short8 b0 = *(const short8*)Kp;
            short8 b1 = *(const short8*)(Kp + 32);
            s[nb] = __builtin_amdgcn_mfma_f32_16x16x32_bf16(qf0, b0, s[nb], 0, 0, 0);
            s[nb] = __builtin_amdgcn_mfma_f32_16x16x32_bf16(qf1, b1, s[nb], 0, 0, 0);
        }
        int row0 = qRow + quad * 4;
        float rmax[4];
        for (int r = 0; r < 4; r++) rmax[r] = -1e30f;
        for (int nb = 0; nb < 4; nb++) {
            int col = kc0 + nb * 16 + lr;
            for (int r = 0; r < 4; r++) {
                if (col > row0 + r) s[nb][r] = -1e30f;
                rmax[r] = fmaxf(rmax[r], s[nb][r]);
            }
        }
        for (int off = 1; off < 16; off <<= 1)
            for (int r = 0; r < 4; r++)
                rmax[r] = fmaxf(rmax[r], __shfl_xor(rmax[r], off));

        float alpha[4], rsum[4];
        for (int r = 0; r < 4; r++) {
            float mn = fmaxf(m_i[r], rmax[r]);
            alpha[r] = __expf(m_i[r] - mn);
            m_i[r] = mn;
            rsum[r] = 0.f;
        }
        for (int nb = 0; nb < 4; nb++) {
            for (int r = 0; r < 4; r++) {
                float p = __expf(s[nb][r] - m_i[r]);
                rsum[r] += p;
                Psh[w][quad * 4 + r][nb * 16 + lr] = (bf16)p;
            }
        }
        for (int off = 1; off < 16; off <<= 1)
            for (int r = 0; r < 4; r++)
                rsum[r] += __shfl_xor(rsum[r], off);
        for (int r = 0; r < 4; r++) l_i[r] = l_i[r] * alpha[r] + rsum[r];
        for (int f = 0; f < 4; f++)
            for (int r = 0; r < 4; r++)
                o[f][r] *= alpha[r];

        __syncthreads();
        short8 p0 = *(const short8*)&Psh[w][lr][quad * 8];
        short8 p1 = *(const short8*)&Psh[w][lr][32 + quad * 8];
        for (int f = 0; f < 4; f++) {
            const bf16* Vp = Vbase + (size_t)(f * 16 + lr) * NT + kc0 + quad * 8;
            short8 v0 = *(const short8*)Vp;
            short8 v1 = *(const short8*)(Vp + 32);
            o[f] = __builtin_amdgcn_mfma_f32_16x16x32_bf16(p0, v0, o[f], 0, 0, 0);
            o[f] = __builtin_amdgcn_mfma_f32_16x16x32_bf16(p1, v1, o[f], 0, 0, 0);
        }
        __syncthreads();
    }

    float inv[4];
    for (int r = 0; r < 4; r++) inv[r] = 1.f / l_i[r];
    for (int f = 0; f < 4; f++) {
        for (int r = 0; r < 4; r++) {
            int t = qRow + quad * 4 + r;
            int d = f * 16 + lr;
            O[((size_t)(b * NT + t)) * NE + h * ND + d] = (bf16)(o[f][r] * inv[r]);
        }
    }
}

extern "C" void kernel_launch(void* const* d_in, const int* in_sizes, int n_in,
                              void* d_out, int out_size, void* d_ws, size_t ws_size,
                              hipStream_t stream)
{
    (void)in_sizes; (void)n_in; (void)out_size; (void)ws_size;
    const void* hs = d_in[0];
    const void* wq = d_in[1];
    const void* bq = d_in[2];
    const void* wk = d_in[3];
    const void* bk = d_in[4];
    const void* wv = d_in[5];
    const void* bv = d_in[6];
    const void* wo = d_in[7];
    const void* bo = d_in[8];
    // d_in[9] = attention_mask: exact causal, applied analytically in attn kernel.

    const size_t qkvElems = (size_t)NBH * NT * ND;   // 8.39M elems, 16MB bf16
    bf16* Qb = (bf16*)d_ws;
    bf16* Kb = Qb + qkvElems;
    bf16* Vt = Kb + qkvElems;                        // [BH,D,T]
    bf16* Ab = Vt + qkvElems;                        // [B,T,E]
    float* sK  = (float*)(Ab + qkvElems);
    float* vSc = sK + NBH * ND;
    float* vZp = vSc + NBH * ND;
    int*   flag = (int*)(vZp + NBH * ND);
    // total ws: 64MB + 96KB + 4B

    dim3 blk(256);
    dim3 gGemm(NE / 128, (NB * NT) / 128);
    const float scaling = 0.125f;  // 64^-0.5

    detect_dtype<<<dim3(1), dim3(64), 0, stream>>>((const unsigned short*)wq, flag);
    gemm_bt<true, 1><<<gGemm, blk, 0, stream>>>(hs, wq, bq, scaling, Qb, flag);
    gemm_bt<true, 1><<<gGemm, blk, 0, stream>>>(hs, wk, bk, 1.0f, Kb, flag);
    gemm_bt<true, 2><<<gGemm, blk, 0, stream>>>(hs, wv, bv, 1.0f, Vt, flag);
    stats_k<<<dim3(NBH), blk, 0, stream>>>(Kb, sK);
    stats_v<<<dim3(NBH), blk, 0, stream>>>(Vt, vSc, vZp);
    quant_qk<<<dim3(NT / 4, NBH), blk, 0, stream>>>(Qb, Kb, sK);
    quant_v<<<dim3(ND, NBH), blk, 0, stream>>>(Vt, vSc, vZp);
    attn<<<dim3(NT / 64, NBH), blk, 0, stream>>>(Qb, Kb, Vt, Ab);
    gemm_bt<false, 0><<<gGemm, blk, 0, stream>>>(Ab, wo, bo, 1.0f, d_out, flag);
}

// Round 3
// 1009.771 us; speedup vs baseline: 1.4805x; 1.4805x over previous
//
#include <hip/hip_runtime.h>
#include <hip/hip_bf16.h>

typedef __hip_bfloat16 bf16;
typedef __attribute__((ext_vector_type(4))) short short4v;
typedef __attribute__((ext_vector_type(8))) short short8;
typedef __attribute__((ext_vector_type(4))) float f32x4;

#define NB 4
#define NT 1024
#define NE 2048
#define NH 32
#define ND 64
#define NBH (NB*NH)

__device__ __forceinline__ short bf16bits(float x) {
    bf16 h = __float2bfloat16(x);
    return *reinterpret_cast<short*>(&h);
}
__device__ __forceinline__ float bitsbf16(short s) {
    bf16 h = *reinterpret_cast<bf16*>(&s);
    return __bfloat162float(h);
}

// Storage-dtype probe: fp32 storage puts pseudo-random mantissa halves at even
// bf16 positions -> some "exponent" >= 0x88 among 512 samples w.p. ~1.
// Real bf16 weights (~N(0,0.02^2)) never trip it. flag=1 -> inputs are fp32.
__global__ void detect_dtype(const unsigned short* __restrict__ w, int* __restrict__ flag) {
    int l = threadIdx.x;
    int big = 0;
    for (int i = l; i < 512; i += 64) {
        unsigned e = (w[i] >> 7) & 0xFFu;
        if (e >= 0x88u) big = 1;
    }
    unsigned long long m = __ballot(big != 0);
    if (l == 0) *flag = (m != 0ULL) ? 1 : 0;
}

// Stage a 128x32 tile (row-major source, row stride NE) into LDS as bf16 [128][32].
// fp32 path converts in-register (4 chunks of 4 floats per thread).
__device__ __forceinline__ void stage_tile(const void* __restrict__ src, bool f32,
                                           int rowBase, int k0, bf16* dst, int tid)
{
    const int K = NE;
    if (f32) {
        int r = tid >> 3;            // 0..31, +32 stride x4
        int c = (tid & 7) * 4;       // 0..28
        const float* p = (const float*)src + (size_t)(rowBase + r) * K + k0 + c;
        bf16* d = dst + r * 32 + c;
        #pragma unroll
        for (int i = 0; i < 4; i++) {
            f32x4 v = *(const f32x4*)(p + (size_t)(i * 32) * K);
            short4v o;
            o[0] = bf16bits(v[0]); o[1] = bf16bits(v[1]);
            o[2] = bf16bits(v[2]); o[3] = bf16bits(v[3]);
            *(short4v*)(d + i * 32 * 32) = o;
        }
    } else {
        int r = tid >> 2;            // 0..63, +64 stride x2
        int c = (tid & 3) * 8;       // 0..24
        const bf16* p = (const bf16*)src + (size_t)(rowBase + r) * K + k0 + c;
        bf16* d = dst + r * 32 + c;
        #pragma unroll
        for (int i = 0; i < 2; i++)
            *(short8*)(d + i * 64 * 32) = *(const short8*)(p + (size_t)(i * 64) * K);
    }
}

// C[m,n] = (sum_k A[m,k]*W[n,k] + bias[n]) * scale   (K = N = NE), LDS-staged 128x128 tile.
// MODE 0: out row-major [M,N], dtype per flag  -> d_out
// MODE 1: out bf16 [B,H,T,D]
// MODE 2: out bf16 [B,H,D,T]   (direct-transposed V)
// A_DYN: A dtype follows flag; false -> A is bf16 workspace.
template<bool A_DYN, int MODE>
__global__ __launch_bounds__(256) void gemm_bt(
    const void* __restrict__ A, const void* __restrict__ W,
    const void* __restrict__ bias, float scale, void* __restrict__ out,
    const int* __restrict__ flagp)
{
    const int K = NE, N = NE;
    const bool f32 = (*flagp != 0);
    __shared__ __align__(16) bf16 As[128 * 32];
    __shared__ __align__(16) bf16 Ws[128 * 32];

    int tid = threadIdx.x;
    int w = tid >> 6, l = tid & 63;
    int lr = l & 15, quad = l >> 4;
    int mBase = blockIdx.y * 128;
    int nBase = blockIdx.x * 128;
    int mw = (w >> 1) * 64, nw = (w & 1) * 64;

    f32x4 acc[4][4] = {};

    for (int k0 = 0; k0 < K; k0 += 32) {
        stage_tile(A, A_DYN && f32, mBase, k0, As, tid);
        stage_tile(W, f32, nBase, k0, Ws, tid);
        __syncthreads();
        short8 af[4], bfr[4];
        #pragma unroll
        for (int i = 0; i < 4; i++)
            af[i] = *(const short8*)(As + (mw + i * 16 + lr) * 32 + quad * 8);
        #pragma unroll
        for (int j = 0; j < 4; j++)
            bfr[j] = *(const short8*)(Ws + (nw + j * 16 + lr) * 32 + quad * 8);
        #pragma unroll
        for (int i = 0; i < 4; i++)
            #pragma unroll
            for (int j = 0; j < 4; j++)
                acc[i][j] = __builtin_amdgcn_mfma_f32_16x16x32_bf16(
                    af[i], bfr[j], acc[i][j], 0, 0, 0);
        __syncthreads();
    }

    #pragma unroll
    for (int i = 0; i < 4; i++) {
        #pragma unroll
        for (int j = 0; j < 4; j++) {
            int n = nBase + nw + j * 16 + lr;
            float bv = f32 ? ((const float*)bias)[n]
                           : bitsbf16(((const short*)bias)[n]);
            #pragma unroll
            for (int r = 0; r < 4; r++) {
                int m = mBase + mw + i * 16 + quad * 4 + r;
                float v = (acc[i][j][r] + bv) * scale;
                if (MODE == 0) {
                    if (f32) ((float*)out)[(size_t)m * N + n] = v;
                    else     ((bf16*)out)[(size_t)m * N + n] = (bf16)v;
                } else {
                    int b = m >> 10, t = m & (NT - 1);
                    int h = n >> 6, d = n & (ND - 1);
                    if (MODE == 1)
                        ((bf16*)out)[(((size_t)(b * NH + h)) * NT + t) * ND + d] = (bf16)v;
                    else
                        ((bf16*)out)[(((size_t)(b * NH + h)) * ND + d) * NT + t] = (bf16)v;
                }
            }
        }
    }
}

// sK[bh,d] = max(1e-5, max_t |K[bh,t,d]|);  K layout [BH,T,D]
__global__ __launch_bounds__(256) void stats_k(
    const bf16* __restrict__ K, float* __restrict__ sK)
{
    int bh = blockIdx.x;
    int d = threadIdx.x & 63, tg = threadIdx.x >> 6;
    const bf16* Kp = K + (size_t)bh * NT * ND;
    float kabs = 0.f;
    for (int t = tg; t < NT; t += 4)
        kabs = fmaxf(kabs, fabsf((float)Kp[t * ND + d]));
    __shared__ float sh[4][64];
    sh[tg][d] = kabs;
    __syncthreads();
    if (threadIdx.x < 64) {
        kabs = fmaxf(fmaxf(sh[0][d], sh[1][d]), fmaxf(sh[2][d], sh[3][d]));
        sK[bh * 64 + d] = fmaxf(kabs, 1e-5f);
    }
}

// Per-channel (over tokens) scale/zero for V; Vt layout [BH,D,T]
__global__ __launch_bounds__(256) void stats_v(
    const bf16* __restrict__ Vt, float* __restrict__ vScale, float* __restrict__ vZero)
{
    int bh = blockIdx.x;
    int c = threadIdx.x >> 2;
    int seg = threadIdx.x & 3;
    const bf16* row = Vt + ((size_t)bh * ND + c) * NT + seg * 256;
    float vmax = 0.f, vmin = 0.f;
    for (int i = 0; i < 256; i += 8) {
        short8 v8 = *(const short8*)(row + i);
        for (int j = 0; j < 8; j++) {
            float f = bitsbf16(v8[j]);
            vmax = fmaxf(vmax, f);
            vmin = fminf(vmin, f);
        }
    }
    vmax = fmaxf(vmax, __shfl_xor(vmax, 1));
    vmax = fmaxf(vmax, __shfl_xor(vmax, 2));
    vmin = fminf(vmin, __shfl_xor(vmin, 1));
    vmin = fminf(vmin, __shfl_xor(vmin, 2));
    if (seg == 0) {
        float sc = (vmax - vmin) * (1.f / 255.f);
        if (sc <= 0.f) sc = 1.f;
        vScale[bh * 64 + c] = sc;
        vZero[bh * 64 + c] = rintf(-vmin / sc);
    }
}

// Per-token (over d=64) fake-quant of Q; smooth+quant of K. In place.
__global__ __launch_bounds__(256) void quant_qk(
    bf16* __restrict__ Q, bf16* __restrict__ K, const float* __restrict__ sK)
{
    int bh = blockIdx.y;
    int t = blockIdx.x * 4 + (threadIdx.x >> 6);
    int l = threadIdx.x & 63;
    size_t idx = ((size_t)bh * NT + t) * ND + l;
    {
        float x = (float)Q[idx];
        float xmax = fmaxf(x, 0.f), xmin = fminf(x, 0.f);
        for (int off = 1; off < 64; off <<= 1) {
            xmax = fmaxf(xmax, __shfl_xor(xmax, off));
            xmin = fminf(xmin, __shfl_xor(xmin, off));
        }
        float sc = (xmax - xmin) * (1.f / 255.f);
        if (sc <= 0.f) sc = 1.f;
        float z = rintf(-xmin / sc);
        float q = fminf(fmaxf(rintf(x / sc) + z, 0.f), 255.f);
        Q[idx] = (bf16)(sc * (q - z));
    }
    {
        float s = sK[bh * 64 + l];
        float x = (float)K[idx] / s;
        float xmax = fmaxf(x, 0.f), xmin = fminf(x, 0.f);
        for (int off = 1; off < 64; off <<= 1) {
            xmax = fmaxf(xmax, __shfl_xor(xmax, off));
            xmin = fminf(xmin, __shfl_xor(xmin, off));
        }
        float sc = (xmax - xmin) * (1.f / 255.f);
        if (sc <= 0.f) sc = 1.f;
        float z = rintf(-xmin / sc);
        float q = fminf(fmaxf(rintf(x / sc) + z, 0.f), 255.f);
        K[idx] = (bf16)(s * (sc * (q - z)));
    }
}

// V fake-quant along tokens, in place on Vt [BH,D,T].
__global__ __launch_bounds__(256) void quant_v(
    bf16* __restrict__ Vt,
    const float* __restrict__ vScale, const float* __restrict__ vZero)
{
    int bh = blockIdx.y, d = blockIdx.x;
    float sc = vScale[bh * 64 + d], z = vZero[bh * 64 + d];
    bf16* row = Vt + ((size_t)bh * ND + d) * NT;
    for (int t = threadIdx.x; t < NT; t += 256) {
        float v = (float)row[t];
        float q = fminf(fmaxf(rintf(v / sc) + z, 0.f), 255.f);
        row[t] = (bf16)(sc * (q - z));
    }
}

// Flash-style causal attention. Q,K: [BH,T,D] bf16 (quantized); Vt: [BH,D,T].
// O: [B,T,E] bf16. Block = 64 Q rows (4 waves x 16), K tiles of 64.
__global__ __launch_bounds__(256) void attn(
    const bf16* __restrict__ Q, const bf16* __restrict__ K,
    const bf16* __restrict__ Vt, bf16* __restrict__ O)
{
    int bh = blockIdx.y;
    int b = bh >> 5, h = bh & 31;
    int qBase = blockIdx.x * 64;
    int w = threadIdx.x >> 6, l = threadIdx.x & 63;
    int lr = l & 15, quad = l >> 4;
    int qRow = qBase + w * 16;

    __shared__ __align__(16) bf16 Psh[4][16][64];

    const bf16* Qp = Q + ((size_t)bh * NT + qRow + lr) * ND + quad * 8;
    short8 qf0 = *(const short8*)(Qp);
    short8 qf1 = *(const short8*)(Qp + 32);

    f32x4 o[4] = {};
    float m_i[4], l_i[4];
    for (int r = 0; r < 4; r++) { m_i[r] = -1e30f; l_i[r] = 0.f; }

    int nkt = (qBase >> 6) + 1;
    const bf16* Kbase = K + (size_t)bh * NT * ND;
    const bf16* Vbase = Vt + (size_t)bh * ND * NT;

    for (int kt = 0; kt < nkt; kt++) {
        int kc0 = kt * 64;
        f32x4 s[4] = {};
        for (int nb = 0; nb < 4; nb++) {
            const bf16* Kp = Kbase + (size_t)(kc0 + nb * 16 + lr) * ND + quad * 8;
            short8 b0 = *(const short8*)Kp;
            short8 b1 = *(const short8*)(Kp + 32);
            s[nb] = __builtin_amdgcn_mfma_f32_16x16x32_bf16(qf0, b0, s[nb], 0, 0, 0);
            s[nb] = __builtin_amdgcn_mfma_f32_16x16x32_bf16(qf1, b1, s[nb], 0, 0, 0);
        }
        int row0 = qRow + quad * 4;
        float rmax[4];
        for (int r = 0; r < 4; r++) rmax[r] = -1e30f;
        for (int nb = 0; nb < 4; nb++) {
            int col = kc0 + nb * 16 + lr;
            for (int r = 0; r < 4; r++) {
                if (col > row0 + r) s[nb][r] = -1e30f;
                rmax[r] = fmaxf(rmax[r], s[nb][r]);
            }
        }
        for (int off = 1; off < 16; off <<= 1)
            for (int r = 0; r < 4; r++)
                rmax[r] = fmaxf(rmax[r], __shfl_xor(rmax[r], off));

        float alpha[4], rsum[4];
        for (int r = 0; r < 4; r++) {
            float mn = fmaxf(m_i[r], rmax[r]);
            alpha[r] = __expf(m_i[r] - mn);
            m_i[r] = mn;
            rsum[r] = 0.f;
        }
        for (int nb = 0; nb < 4; nb++) {
            for (int r = 0; r < 4; r++) {
                float p = __expf(s[nb][r] - m_i[r]);
                rsum[r] += p;
                Psh[w][quad * 4 + r][nb * 16 + lr] = (bf16)p;
            }
        }
        for (int off = 1; off < 16; off <<= 1)
            for (int r = 0; r < 4; r++)
                rsum[r] += __shfl_xor(rsum[r], off);
        for (int r = 0; r < 4; r++) l_i[r] = l_i[r] * alpha[r] + rsum[r];
        for (int f = 0; f < 4; f++)
            for (int r = 0; r < 4; r++)
                o[f][r] *= alpha[r];

        __syncthreads();
        short8 p0 = *(const short8*)&Psh[w][lr][quad * 8];
        short8 p1 = *(const short8*)&Psh[w][lr][32 + quad * 8];
        for (int f = 0; f < 4; f++) {
            const bf16* Vp = Vbase + (size_t)(f * 16 + lr) * NT + kc0 + quad * 8;
            short8 v0 = *(const short8*)Vp;
            short8 v1 = *(const short8*)(Vp + 32);
            o[f] = __builtin_amdgcn_mfma_f32_16x16x32_bf16(p0, v0, o[f], 0, 0, 0);
            o[f] = __builtin_amdgcn_mfma_f32_16x16x32_bf16(p1, v1, o[f], 0, 0, 0);
        }
        __syncthreads();
    }

    float inv[4];
    for (int r = 0; r < 4; r++) inv[r] = 1.f / l_i[r];
    for (int f = 0; f < 4; f++) {
        for (int r = 0; r < 4; r++) {
            int t = qRow + quad * 4 + r;
            int d = f * 16 + lr;
            O[((size_t)(b * NT + t)) * NE + h * ND + d] = (bf16)(o[f][r] * inv[r]);
        }
    }
}

extern "C" void kernel_launch(void* const* d_in, const int* in_sizes, int n_in,
                              void* d_out, int out_size, void* d_ws, size_t ws_size,
                              hipStream_t stream)
{
    (void)in_sizes; (void)n_in; (void)out_size; (void)ws_size;
    const void* hs = d_in[0];
    const void* wq = d_in[1];
    const void* bq = d_in[2];
    const void* wk = d_in[3];
    const void* bk = d_in[4];
    const void* wv = d_in[5];
    const void* bv = d_in[6];
    const void* wo = d_in[7];
    const void* bo = d_in[8];
    // d_in[9] = attention_mask: exact causal, applied analytically in attn kernel.

    const size_t qkvElems = (size_t)NBH * NT * ND;   // 8.39M elems, 16MB bf16
    bf16* Qb = (bf16*)d_ws;
    bf16* Kb = Qb + qkvElems;
    bf16* Vt = Kb + qkvElems;                        // [BH,D,T]
    bf16* Ab = Vt + qkvElems;                        // [B,T,E]
    float* sK  = (float*)(Ab + qkvElems);
    float* vSc = sK + NBH * ND;
    float* vZp = vSc + NBH * ND;
    int*   flag = (int*)(vZp + NBH * ND);

    dim3 blk(256);
    dim3 gGemm(NE / 128, (NB * NT) / 128);
    const float scaling = 0.125f;  // 64^-0.5

    detect_dtype<<<dim3(1), dim3(64), 0, stream>>>((const unsigned short*)wq, flag);
    gemm_bt<true, 1><<<gGemm, blk, 0, stream>>>(hs, wq, bq, scaling, Qb, flag);
    gemm_bt<true, 1><<<gGemm, blk, 0, stream>>>(hs, wk, bk, 1.0f, Kb, flag);
    gemm_bt<true, 2><<<gGemm, blk, 0, stream>>>(hs, wv, bv, 1.0f, Vt, flag);
    stats_k<<<dim3(NBH), blk, 0, stream>>>(Kb, sK);
    stats_v<<<dim3(NBH), blk, 0, stream>>>(Vt, vSc, vZp);
    quant_qk<<<dim3(NT / 4, NBH), blk, 0, stream>>>(Qb, Kb, sK);
    quant_v<<<dim3(ND, NBH), blk, 0, stream>>>(Vt, vSc, vZp);
    attn<<<dim3(NT / 64, NBH), blk, 0, stream>>>(Qb, Kb, Vt, Ab);
    gemm_bt<false, 0><<<gGemm, blk, 0, stream>>>(Ab, wo, bo, 1.0f, d_out, flag);
}

// Round 4
// 536.766 us; speedup vs baseline: 2.7852x; 1.8812x over previous
//
#include <hip/hip_runtime.h>
#include <hip/hip_bf16.h>

typedef __hip_bfloat16 bf16;
typedef __attribute__((ext_vector_type(4))) short short4v;
typedef __attribute__((ext_vector_type(8))) short short8;
typedef __attribute__((ext_vector_type(4))) float f32x4;

#define NB 4
#define NT 1024
#define NE 2048
#define NH 32
#define ND 64
#define NBH (NB*NH)

__device__ __forceinline__ short bf16bits(float x) {
    bf16 h = __float2bfloat16(x);
    return *reinterpret_cast<short*>(&h);
}
__device__ __forceinline__ float bitsbf16(short s) {
    bf16 h = *reinterpret_cast<bf16*>(&s);
    return __bfloat162float(h);
}

// async global->LDS, 16B per lane; LDS dest is wave-uniform base + lane*16.
__device__ __forceinline__ void gll16(const bf16* g, bf16* l) {
    __builtin_amdgcn_global_load_lds(
        (const __attribute__((address_space(1))) unsigned int*)g,
        (__attribute__((address_space(3))) unsigned int*)l, 16, 0, 0);
}

// Storage-dtype probe (flag=1 -> inputs are fp32). See round-2 notes.
__global__ void detect_dtype(const unsigned short* __restrict__ w, int* __restrict__ flag) {
    int l = threadIdx.x;
    int big = 0;
    for (int i = l; i < 512; i += 64) {
        unsigned e = (w[i] >> 7) & 0xFFu;
        if (e >= 0x88u) big = 1;
    }
    unsigned long long m = __ballot(big != 0);
    if (l == 0) *flag = (m != 0ULL) ? 1 : 0;
}

// Elementwise convert (or copy) src -> bf16 dst. 8 elems/thread; grid sized exactly.
__global__ __launch_bounds__(256) void conv_bf16(
    const void* __restrict__ src, bf16* __restrict__ dst, const int* __restrict__ flagp)
{
    const bool f32 = (*flagp != 0);
    size_t i = ((size_t)blockIdx.x * 256 + threadIdx.x) * 8;
    if (f32) {
        const float* s = (const float*)src + i;
        f32x4 a = *(const f32x4*)s;
        f32x4 b = *(const f32x4*)(s + 4);
        short8 r;
        r[0] = bf16bits(a[0]); r[1] = bf16bits(a[1]);
        r[2] = bf16bits(a[2]); r[3] = bf16bits(a[3]);
        r[4] = bf16bits(b[0]); r[5] = bf16bits(b[1]);
        r[6] = bf16bits(b[2]); r[7] = bf16bits(b[3]);
        *(short8*)(dst + i) = r;
    } else {
        *(short8*)(dst + i) = *(const short8*)((const bf16*)src + i);
    }
}

// ---------------- fast-path GEMM: bf16 A/W, global_load_lds staging ----------------
// C[m,n] = (sum_k A[m,k]*W[n,k] + bias[n]) * scale   (K = N = NE)
// MODE 0: out row-major [M,N], dtype per flag   MODE 1: bf16 [B,H,T,D]   MODE 2: bf16 [B,H,D,T]
// FUSE 0: none  1: per-token fake-quant of output (Q)  2: abs-max col stats (K)  3: min/max col stats (V)
template<int MODE, int FUSE>
__global__ __launch_bounds__(256) void gemm_bf16(
    const bf16* __restrict__ A, const bf16* __restrict__ W,
    const void* __restrict__ bias, float scale, void* __restrict__ out,
    const int* __restrict__ flagp, int* __restrict__ st0, int* __restrict__ st1)
{
    const int K = NE, N = NE;
    __shared__ __align__(16) bf16 As[128 * 32];
    __shared__ __align__(16) bf16 Ws[128 * 32];
    int tid = threadIdx.x;
    int w = tid >> 6, l = tid & 63;
    int lr = l & 15, quad = l >> 4;
    int mBase = blockIdx.y * 128, nBase = blockIdx.x * 128;
    int mw = (w >> 1) * 64, nw = (w & 1) * 64;
    f32x4 acc[4][4] = {};

    const bf16* Ag = A + (size_t)(mBase + w * 16 + (l >> 2)) * K + (l & 3) * 8;
    const bf16* Wg = W + (size_t)(nBase + w * 16 + (l >> 2)) * K + (l & 3) * 8;
    bf16* AsW = As + (w * 16) * 32;
    bf16* WsW = Ws + (w * 16) * 32;

    for (int k0 = 0; k0 < K; k0 += 32) {
        gll16(Ag + k0, AsW);
        gll16(Ag + (size_t)64 * K + k0, AsW + 64 * 32);
        gll16(Wg + k0, WsW);
        gll16(Wg + (size_t)64 * K + k0, WsW + 64 * 32);
        __syncthreads();
        short8 af[4], bfr[4];
        #pragma unroll
        for (int i = 0; i < 4; i++)
            af[i] = *(const short8*)(As + (mw + i * 16 + lr) * 32 + quad * 8);
        #pragma unroll
        for (int j = 0; j < 4; j++)
            bfr[j] = *(const short8*)(Ws + (nw + j * 16 + lr) * 32 + quad * 8);
        #pragma unroll
        for (int i = 0; i < 4; i++)
            #pragma unroll
            for (int j = 0; j < 4; j++)
                acc[i][j] = __builtin_amdgcn_mfma_f32_16x16x32_bf16(
                    af[i], bfr[j], acc[i][j], 0, 0, 0);
        __syncthreads();
    }

    const bool f32 = (*flagp != 0);
    float bv[4];
    #pragma unroll
    for (int j = 0; j < 4; j++) {
        int n = nBase + nw + j * 16 + lr;
        bv[j] = f32 ? ((const float*)bias)[n] : bitsbf16(((const short*)bias)[n]);
    }
    float colA[4] = {0.f, 0.f, 0.f, 0.f};
    float colB[4] = {0.f, 0.f, 0.f, 0.f};

    #pragma unroll
    for (int i = 0; i < 4; i++) {
        float v[4][4];
        #pragma unroll
        for (int j = 0; j < 4; j++)
            #pragma unroll
            for (int r = 0; r < 4; r++)
                v[j][r] = (acc[i][j][r] + bv[j]) * scale;

        if (FUSE == 1) {
            // per-row (token) fake-quant over this wave's 64 cols (= one head's d-range)
            #pragma unroll
            for (int r = 0; r < 4; r++) {
                float mx = 0.f, mn = 0.f;
                #pragma unroll
                for (int j = 0; j < 4; j++) { mx = fmaxf(mx, v[j][r]); mn = fminf(mn, v[j][r]); }
                #pragma unroll
                for (int off = 1; off < 16; off <<= 1) {
                    mx = fmaxf(mx, __shfl_xor(mx, off));
                    mn = fminf(mn, __shfl_xor(mn, off));
                }
                float sc = (mx - mn) * (1.f / 255.f);
                if (sc <= 0.f) sc = 1.f;
                float z = rintf(-mn / sc);
                #pragma unroll
                for (int j = 0; j < 4; j++) {
                    float q = fminf(fmaxf(rintf(v[j][r] / sc) + z, 0.f), 255.f);
                    v[j][r] = sc * (q - z);
                }
            }
        }
        if (FUSE == 2) {
            #pragma unroll
            for (int j = 0; j < 4; j++)
                #pragma unroll
                for (int r = 0; r < 4; r++)
                    colA[j] = fmaxf(colA[j], fabsf(v[j][r]));
        }
        if (FUSE == 3) {
            #pragma unroll
            for (int j = 0; j < 4; j++)
                #pragma unroll
                for (int r = 0; r < 4; r++) {
                    colA[j] = fmaxf(colA[j], v[j][r]);
                    colB[j] = fmaxf(colB[j], -v[j][r]);
                }
        }

        #pragma unroll
        for (int j = 0; j < 4; j++) {
            int n = nBase + nw + j * 16 + lr;
            #pragma unroll
            for (int r = 0; r < 4; r++) {
                int m = mBase + mw + i * 16 + quad * 4 + r;
                float vv = v[j][r];
                if (MODE == 0) {
                    if (f32) ((float*)out)[(size_t)m * N + n] = vv;
                    else     ((bf16*)out)[(size_t)m * N + n] = (bf16)vv;
                } else {
                    int b = m >> 10, t = m & (NT - 1);
                    int h = n >> 6, d = n & (ND - 1);
                    if (MODE == 1)
                        ((bf16*)out)[(((size_t)(b * NH + h)) * NT + t) * ND + d] = (bf16)vv;
                    else
                        ((bf16*)out)[(((size_t)(b * NH + h)) * ND + d) * NT + t] = (bf16)vv;
                }
            }
        }
    }

    if (FUSE == 2 || FUSE == 3) {
        int b = mBase >> 10;
        #pragma unroll
        for (int j = 0; j < 4; j++) {
            float a = colA[j], c = colB[j];
            a = fmaxf(a, __shfl_xor(a, 16)); a = fmaxf(a, __shfl_xor(a, 32));
            if (FUSE == 3) { c = fmaxf(c, __shfl_xor(c, 16)); c = fmaxf(c, __shfl_xor(c, 32)); }
            if (quad == 0) {
                int n = nBase + nw + j * 16 + lr;
                int idx = (b * NH + (n >> 6)) * 64 + (n & 63);
                atomicMax(st0 + idx, __float_as_int(a));
                if (FUSE == 3) atomicMax(st1 + idx, __float_as_int(c));
            }
        }
    }
}

// K smooth + per-token fake-quant, in place. sK from atomics (raw max|k| bits).
__global__ __launch_bounds__(256) void quant_k(
    bf16* __restrict__ Kb, const int* __restrict__ sKbits)
{
    int bh = blockIdx.y;
    int t = blockIdx.x * 4 + (threadIdx.x >> 6);
    int l = threadIdx.x & 63;
    size_t idx = ((size_t)bh * NT + t) * ND + l;
    float s = fmaxf(__int_as_float(sKbits[bh * 64 + l]), 1e-5f);
    float x = (float)Kb[idx] / s;
    float mx = fmaxf(x, 0.f), mn = fminf(x, 0.f);
    #pragma unroll
    for (int off = 1; off < 64; off <<= 1) {
        mx = fmaxf(mx, __shfl_xor(mx, off));
        mn = fminf(mn, __shfl_xor(mn, off));
    }
    float sc = (mx - mn) * (1.f / 255.f);
    if (sc <= 0.f) sc = 1.f;
    float z = rintf(-mn / sc);
    float q = fminf(fmaxf(rintf(x / sc) + z, 0.f), 255.f);
    Kb[idx] = (bf16)(s * (sc * (q - z)));
}

// V fake-quant along tokens, vectorized, in place on Vt [BH,D,T].
__global__ __launch_bounds__(256) void quant_v2(
    bf16* __restrict__ Vt, const int* __restrict__ vMax, const int* __restrict__ vNeg)
{
    int bh = blockIdx.y;
    int d = blockIdx.x * 8 + (threadIdx.x >> 5);
    int c = (threadIdx.x & 31) * 8;
    float mx = __int_as_float(vMax[bh * 64 + d]);
    float mn = -__int_as_float(vNeg[bh * 64 + d]);
    float sc = (mx - mn) * (1.f / 255.f);
    if (sc <= 0.f) sc = 1.f;
    float z = rintf(-mn / sc);
    bf16* row = Vt + ((size_t)bh * ND + d) * NT;
    for (int seg = 0; seg < 4; seg++) {
        int off = seg * 256 + c;
        short8 v8 = *(const short8*)(row + off);
        #pragma unroll
        for (int k = 0; k < 8; k++) {
            float f = bitsbf16(v8[k]);
            float q = fminf(fmaxf(rintf(f / sc) + z, 0.f), 255.f);
            v8[k] = bf16bits(sc * (q - z));
        }
        *(short8*)(row + off) = v8;
    }
}

// Flash-style causal attention with double-buffered LDS K/V staging.
// Q,K: [BH,T,D] bf16 (quantized); Vt: [BH,D,T]. O: [B,T,E] bf16.
__global__ __launch_bounds__(256) void attn2(
    const bf16* __restrict__ Q, const bf16* __restrict__ K,
    const bf16* __restrict__ Vt, bf16* __restrict__ O)
{
    int bh = blockIdx.y;
    int b = bh >> 5, h = bh & 31;
    int qb = (int)gridDim.x - 1 - (int)blockIdx.x;   // heavy blocks first
    int qBase = qb * 64;
    int w = threadIdx.x >> 6, l = threadIdx.x & 63;
    int lr = l & 15, quad = l >> 4;
    int qRow = qBase + w * 16;

    __shared__ __align__(16) bf16 Ks[2][64 * 64];
    __shared__ __align__(16) bf16 Vs[2][64 * 64];
    __shared__ __align__(16) bf16 Psh[4][16 * 64];

    const bf16* Kbase = K + (size_t)bh * NT * ND;
    const bf16* Vbase = Vt + (size_t)bh * ND * NT;

    const bf16* Qp = Q + ((size_t)bh * NT + qRow + lr) * ND + quad * 8;
    short8 qf0 = *(const short8*)Qp;
    short8 qf1 = *(const short8*)(Qp + 32);

    f32x4 o[4] = {};
    float m_i[4], l_i[4];
    #pragma unroll
    for (int r = 0; r < 4; r++) { m_i[r] = -1e30f; l_i[r] = 0.f; }

    int nkt = qb + 1;
    int srow = w * 16 + (l >> 3);   // within-tile row (K: token, V: d)
    int scol = (l & 7) * 8;         // within-row element offset

    // stage tile kt into buffer bufi: K tile rows are contiguous 128B; V rows stride NT.
    auto stage = [&](int kt, int bufi) {
        int kc0 = kt * 64;
        #pragma unroll
        for (int c = 0; c < 2; c++) {
            gll16(Kbase + (size_t)(kc0 + srow + c * 8) * ND + scol,
                  &Ks[bufi][(w * 16 + c * 8) * 64]);
            gll16(Vbase + (size_t)(srow + c * 8) * NT + kc0 + scol,
                  &Vs[bufi][(w * 16 + c * 8) * 64]);
        }
    };
    stage(0, 0);

    for (int kt = 0; kt < nkt; kt++) {
        __syncthreads();               // buf[kt&1] staged (vmcnt drained); prev-iter LDS reads done
        if (kt + 1 < nkt) stage(kt + 1, (kt + 1) & 1);
        const bf16* Kt = Ks[kt & 1];
        const bf16* Vv = Vs[kt & 1];
        int kc0 = kt * 64;

        f32x4 s[4] = {};
        #pragma unroll
        for (int nb = 0; nb < 4; nb++) {
            short8 b0 = *(const short8*)(Kt + (nb * 16 + lr) * 64 + quad * 8);
            short8 b1 = *(const short8*)(Kt + (nb * 16 + lr) * 64 + 32 + quad * 8);
            s[nb] = __builtin_amdgcn_mfma_f32_16x16x32_bf16(qf0, b0, s[nb], 0, 0, 0);
            s[nb] = __builtin_amdgcn_mfma_f32_16x16x32_bf16(qf1, b1, s[nb], 0, 0, 0);
        }

        int row0 = qRow + quad * 4;
        float rmax[4];
        #pragma unroll
        for (int r = 0; r < 4; r++) rmax[r] = -1e30f;
        #pragma unroll
        for (int nb = 0; nb < 4; nb++) {
            int col = kc0 + nb * 16 + lr;
            #pragma unroll
            for (int r = 0; r < 4; r++) {
                if (col > row0 + r) s[nb][r] = -1e30f;
                rmax[r] = fmaxf(rmax[r], s[nb][r]);
            }
        }
        #pragma unroll
        for (int off = 1; off < 16; off <<= 1)
            #pragma unroll
            for (int r = 0; r < 4; r++)
                rmax[r] = fmaxf(rmax[r], __shfl_xor(rmax[r], off));

        float alpha[4], rsum[4];
        #pragma unroll
        for (int r = 0; r < 4; r++) {
            float mn2 = fmaxf(m_i[r], rmax[r]);
            alpha[r] = __expf(m_i[r] - mn2);
            m_i[r] = mn2;
            rsum[r] = 0.f;
        }
        #pragma unroll
        for (int nb = 0; nb < 4; nb++)
            #pragma unroll
            for (int r = 0; r < 4; r++) {
                float pp = __expf(s[nb][r] - m_i[r]);
                rsum[r] += pp;
                Psh[w][(quad * 4 + r) * 64 + nb * 16 + lr] = (bf16)pp;
            }
        #pragma unroll
        for (int off = 1; off < 16; off <<= 1)
            #pragma unroll
            for (int r = 0; r < 4; r++)
                rsum[r] += __shfl_xor(rsum[r], off);
        #pragma unroll
        for (int r = 0; r < 4; r++) l_i[r] = l_i[r] * alpha[r] + rsum[r];
        #pragma unroll
        for (int f = 0; f < 4; f++)
            #pragma unroll
            for (int r = 0; r < 4; r++)
                o[f][r] *= alpha[r];

        __syncthreads();               // Psh visible
        short8 p0 = *(const short8*)(&Psh[w][lr * 64 + quad * 8]);
        short8 p1 = *(const short8*)(&Psh[w][lr * 64 + 32 + quad * 8]);
        #pragma unroll
        for (int f = 0; f < 4; f++) {
            short8 v0 = *(const short8*)(Vv + (f * 16 + lr) * 64 + quad * 8);
            short8 v1 = *(const short8*)(Vv + (f * 16 + lr) * 64 + 32 + quad * 8);
            o[f] = __builtin_amdgcn_mfma_f32_16x16x32_bf16(p0, v0, o[f], 0, 0, 0);
            o[f] = __builtin_amdgcn_mfma_f32_16x16x32_bf16(p1, v1, o[f], 0, 0, 0);
        }
    }

    float inv[4];
    #pragma unroll
    for (int r = 0; r < 4; r++) inv[r] = 1.f / l_i[r];
    #pragma unroll
    for (int f = 0; f < 4; f++)
        #pragma unroll
        for (int r = 0; r < 4; r++) {
            int t = qRow + quad * 4 + r;
            int d = f * 16 + lr;
            O[((size_t)(b * NT + t)) * NE + h * ND + d] = (bf16)(o[f][r] * inv[r]);
        }
}

// ---------------- fallback path (round-3, validated; used if ws too small) ----------------
__device__ __forceinline__ short8 ldfrag(const void* base, size_t off, bool f32) {
    if (f32) {
        const float* p = (const float*)base + off;
        f32x4 a = *(const f32x4*)p;
        f32x4 b = *(const f32x4*)(p + 4);
        short8 r;
        r[0] = bf16bits(a[0]); r[1] = bf16bits(a[1]);
        r[2] = bf16bits(a[2]); r[3] = bf16bits(a[3]);
        r[4] = bf16bits(b[0]); r[5] = bf16bits(b[1]);
        r[6] = bf16bits(b[2]); r[7] = bf16bits(b[3]);
        return r;
    }
    return *(const short8*)((const bf16*)base + off);
}

__device__ __forceinline__ void stage_tile(const void* __restrict__ src, bool f32,
                                           int rowBase, int k0, bf16* dst, int tid)
{
    const int K = NE;
    if (f32) {
        int r = tid >> 3;
        int c = (tid & 7) * 4;
        const float* p = (const float*)src + (size_t)(rowBase + r) * K + k0 + c;
        bf16* d = dst + r * 32 + c;
        #pragma unroll
        for (int i = 0; i < 4; i++) {
            f32x4 v = *(const f32x4*)(p + (size_t)(i * 32) * K);
            short4v o;
            o[0] = bf16bits(v[0]); o[1] = bf16bits(v[1]);
            o[2] = bf16bits(v[2]); o[3] = bf16bits(v[3]);
            *(short4v*)(d + i * 32 * 32) = o;
        }
    } else {
        int r = tid >> 2;
        int c = (tid & 3) * 8;
        const bf16* p = (const bf16*)src + (size_t)(rowBase + r) * K + k0 + c;
        bf16* d = dst + r * 32 + c;
        #pragma unroll
        for (int i = 0; i < 2; i++)
            *(short8*)(d + i * 64 * 32) = *(const short8*)(p + (size_t)(i * 64) * K);
    }
}

template<bool A_DYN, int MODE>
__global__ __launch_bounds__(256) void gemm_bt(
    const void* __restrict__ A, const void* __restrict__ W,
    const void* __restrict__ bias, float scale, void* __restrict__ out,
    const int* __restrict__ flagp)
{
    const int K = NE, N = NE;
    const bool f32 = (*flagp != 0);
    __shared__ __align__(16) bf16 As[128 * 32];
    __shared__ __align__(16) bf16 Ws[128 * 32];
    int tid = threadIdx.x;
    int w = tid >> 6, l = tid & 63;
    int lr = l & 15, quad = l >> 4;
    int mBase = blockIdx.y * 128;
    int nBase = blockIdx.x * 128;
    int mw = (w >> 1) * 64, nw = (w & 1) * 64;
    f32x4 acc[4][4] = {};
    for (int k0 = 0; k0 < K; k0 += 32) {
        stage_tile(A, A_DYN && f32, mBase, k0, As, tid);
        stage_tile(W, f32, nBase, k0, Ws, tid);
        __syncthreads();
        short8 af[4], bfr[4];
        #pragma unroll
        for (int i = 0; i < 4; i++)
            af[i] = *(const short8*)(As + (mw + i * 16 + lr) * 32 + quad * 8);
        #pragma unroll
        for (int j = 0; j < 4; j++)
            bfr[j] = *(const short8*)(Ws + (nw + j * 16 + lr) * 32 + quad * 8);
        #pragma unroll
        for (int i = 0; i < 4; i++)
            #pragma unroll
            for (int j = 0; j < 4; j++)
                acc[i][j] = __builtin_amdgcn_mfma_f32_16x16x32_bf16(
                    af[i], bfr[j], acc[i][j], 0, 0, 0);
        __syncthreads();
    }
    #pragma unroll
    for (int i = 0; i < 4; i++) {
        #pragma unroll
        for (int j = 0; j < 4; j++) {
            int n = nBase + nw + j * 16 + lr;
            float bv = f32 ? ((const float*)bias)[n] : bitsbf16(((const short*)bias)[n]);
            #pragma unroll
            for (int r = 0; r < 4; r++) {
                int m = mBase + mw + i * 16 + quad * 4 + r;
                float v = (acc[i][j][r] + bv) * scale;
                if (MODE == 0) {
                    if (f32) ((float*)out)[(size_t)m * N + n] = v;
                    else     ((bf16*)out)[(size_t)m * N + n] = (bf16)v;
                } else {
                    int b = m >> 10, t = m & (NT - 1);
                    int h = n >> 6, d = n & (ND - 1);
                    if (MODE == 1)
                        ((bf16*)out)[(((size_t)(b * NH + h)) * NT + t) * ND + d] = (bf16)v;
                    else
                        ((bf16*)out)[(((size_t)(b * NH + h)) * ND + d) * NT + t] = (bf16)v;
                }
            }
        }
    }
}

__global__ __launch_bounds__(256) void stats_k(
    const bf16* __restrict__ K, float* __restrict__ sK)
{
    int bh = blockIdx.x;
    int d = threadIdx.x & 63, tg = threadIdx.x >> 6;
    const bf16* Kp = K + (size_t)bh * NT * ND;
    float kabs = 0.f;
    for (int t = tg; t < NT; t += 4)
        kabs = fmaxf(kabs, fabsf((float)Kp[t * ND + d]));
    __shared__ float sh[4][64];
    sh[tg][d] = kabs;
    __syncthreads();
    if (threadIdx.x < 64) {
        kabs = fmaxf(fmaxf(sh[0][d], sh[1][d]), fmaxf(sh[2][d], sh[3][d]));
        sK[bh * 64 + d] = fmaxf(kabs, 1e-5f);
    }
}

__global__ __launch_bounds__(256) void stats_v(
    const bf16* __restrict__ Vt, float* __restrict__ vScale, float* __restrict__ vZero)
{
    int bh = blockIdx.x;
    int c = threadIdx.x >> 2;
    int seg = threadIdx.x & 3;
    const bf16* row = Vt + ((size_t)bh * ND + c) * NT + seg * 256;
    float vmax = 0.f, vmin = 0.f;
    for (int i = 0; i < 256; i += 8) {
        short8 v8 = *(const short8*)(row + i);
        for (int j = 0; j < 8; j++) {
            float f = bitsbf16(v8[j]);
            vmax = fmaxf(vmax, f);
            vmin = fminf(vmin, f);
        }
    }
    vmax = fmaxf(vmax, __shfl_xor(vmax, 1));
    vmax = fmaxf(vmax, __shfl_xor(vmax, 2));
    vmin = fminf(vmin, __shfl_xor(vmin, 1));
    vmin = fminf(vmin, __shfl_xor(vmin, 2));
    if (seg == 0) {
        float sc = (vmax - vmin) * (1.f / 255.f);
        if (sc <= 0.f) sc = 1.f;
        vScale[bh * 64 + c] = sc;
        vZero[bh * 64 + c] = rintf(-vmin / sc);
    }
}

__global__ __launch_bounds__(256) void quant_qk(
    bf16* __restrict__ Q, bf16* __restrict__ K, const float* __restrict__ sK)
{
    int bh = blockIdx.y;
    int t = blockIdx.x * 4 + (threadIdx.x >> 6);
    int l = threadIdx.x & 63;
    size_t idx = ((size_t)bh * NT + t) * ND + l;
    {
        float x = (float)Q[idx];
        float xmax = fmaxf(x, 0.f), xmin = fminf(x, 0.f);
        for (int off = 1; off < 64; off <<= 1) {
            xmax = fmaxf(xmax, __shfl_xor(xmax, off));
            xmin = fminf(xmin, __shfl_xor(xmin, off));
        }
        float sc = (xmax - xmin) * (1.f / 255.f);
        if (sc <= 0.f) sc = 1.f;
        float z = rintf(-xmin / sc);
        float q = fminf(fmaxf(rintf(x / sc) + z, 0.f), 255.f);
        Q[idx] = (bf16)(sc * (q - z));
    }
    {
        float s = sK[bh * 64 + l];
        float x = (float)K[idx] / s;
        float xmax = fmaxf(x, 0.f), xmin = fminf(x, 0.f);
        for (int off = 1; off < 64; off <<= 1) {
            xmax = fmaxf(xmax, __shfl_xor(xmax, off));
            xmin = fminf(xmin, __shfl_xor(xmin, off));
        }
        float sc = (xmax - xmin) * (1.f / 255.f);
        if (sc <= 0.f) sc = 1.f;
        float z = rintf(-xmin / sc);
        float q = fminf(fmaxf(rintf(x / sc) + z, 0.f), 255.f);
        K[idx] = (bf16)(s * (sc * (q - z)));
    }
}

__global__ __launch_bounds__(256) void quant_v_old(
    bf16* __restrict__ Vt,
    const float* __restrict__ vScale, const float* __restrict__ vZero)
{
    int bh = blockIdx.y, d = blockIdx.x;
    float sc = vScale[bh * 64 + d], z = vZero[bh * 64 + d];
    bf16* row = Vt + ((size_t)bh * ND + d) * NT;
    for (int t = threadIdx.x; t < NT; t += 256) {
        float v = (float)row[t];
        float q = fminf(fmaxf(rintf(v / sc) + z, 0.f), 255.f);
        row[t] = (bf16)(sc * (q - z));
    }
}

extern "C" void kernel_launch(void* const* d_in, const int* in_sizes, int n_in,
                              void* d_out, int out_size, void* d_ws, size_t ws_size,
                              hipStream_t stream)
{
    (void)in_sizes; (void)n_in; (void)out_size;
    const void* hs = d_in[0];
    const void* wq = d_in[1];
    const void* bq = d_in[2];
    const void* wk = d_in[3];
    const void* bk = d_in[4];
    const void* wv = d_in[5];
    const void* bv = d_in[6];
    const void* wo = d_in[7];
    const void* bo = d_in[8];
    // d_in[9] = attention_mask: exact causal, applied analytically.

    const size_t qkvE = (size_t)NBH * NT * ND;       // 8.39M elems
    const size_t qkvB = qkvE * 2;                    // 16.78 MB
    const size_t wBy  = (size_t)NE * NE * 2;         // 8.39 MB
    const size_t statB = 3 * (size_t)NBH * ND * 4;   // 96 KB
    const size_t needFast = 4 * qkvB + 4 * wBy + statB + 256;

    dim3 blk(256);
    dim3 gG(NE / 128, (NB * NT) / 128);
    const float scaling = 0.125f;  // 64^-0.5

    if (ws_size >= needFast) {
        char* p = (char*)d_ws;
        bf16* Qb  = (bf16*)p; p += qkvB;
        bf16* Kb  = (bf16*)p; p += qkvB;
        bf16* Vt  = (bf16*)p; p += qkvB;
        bf16* hsB = (bf16*)p; p += qkvB;             // reused as Ab after QKV
        bf16* wqB = (bf16*)p; p += wBy;
        bf16* wkB = (bf16*)p; p += wBy;
        bf16* wvB = (bf16*)p; p += wBy;
        bf16* woB = (bf16*)p; p += wBy;
        int* sKb = (int*)p;
        int* vMx = sKb + NBH * ND;
        int* vNg = vMx + NBH * ND;
        int* flag = vNg + NBH * ND;
        bf16* Ab = hsB;

        detect_dtype<<<dim3(1), dim3(64), 0, stream>>>((const unsigned short*)wq, flag);
        hipMemsetAsync(sKb, 0, statB, stream);
        conv_bf16<<<dim3(4096), blk, 0, stream>>>(hs, hsB, flag);
        conv_bf16<<<dim3(2048), blk, 0, stream>>>(wq, wqB, flag);
        conv_bf16<<<dim3(2048), blk, 0, stream>>>(wk, wkB, flag);
        conv_bf16<<<dim3(2048), blk, 0, stream>>>(wv, wvB, flag);
        conv_bf16<<<dim3(2048), blk, 0, stream>>>(wo, woB, flag);
        gemm_bf16<1, 1><<<gG, blk, 0, stream>>>(hsB, wqB, bq, scaling, Qb, flag, nullptr, nullptr);
        gemm_bf16<1, 2><<<gG, blk, 0, stream>>>(hsB, wkB, bk, 1.0f, Kb, flag, sKb, nullptr);
        gemm_bf16<2, 3><<<gG, blk, 0, stream>>>(hsB, wvB, bv, 1.0f, Vt, flag, vMx, vNg);
        quant_k<<<dim3(NT / 4, NBH), blk, 0, stream>>>(Kb, sKb);
        quant_v2<<<dim3(ND / 8, NBH), blk, 0, stream>>>(Vt, vMx, vNg);
        attn2<<<dim3(NT / 64, NBH), blk, 0, stream>>>(Qb, Kb, Vt, Ab);
        gemm_bf16<0, 0><<<gG, blk, 0, stream>>>(Ab, woB, bo, 1.0f, d_out, flag, nullptr, nullptr);
    } else {
        bf16* Qb = (bf16*)d_ws;
        bf16* Kb = Qb + qkvE;
        bf16* Vt = Kb + qkvE;
        bf16* Ab = Vt + qkvE;
        float* sK  = (float*)(Ab + qkvE);
        float* vSc = sK + NBH * ND;
        float* vZp = vSc + NBH * ND;
        int*   flag = (int*)(vZp + NBH * ND);

        detect_dtype<<<dim3(1), dim3(64), 0, stream>>>((const unsigned short*)wq, flag);
        gemm_bt<true, 1><<<gG, blk, 0, stream>>>(hs, wq, bq, scaling, Qb, flag);
        gemm_bt<true, 1><<<gG, blk, 0, stream>>>(hs, wk, bk, 1.0f, Kb, flag);
        gemm_bt<true, 2><<<gG, blk, 0, stream>>>(hs, wv, bv, 1.0f, Vt, flag);
        stats_k<<<dim3(NBH), blk, 0, stream>>>(Kb, sK);
        stats_v<<<dim3(NBH), blk, 0, stream>>>(Vt, vSc, vZp);
        quant_qk<<<dim3(NT / 4, NBH), blk, 0, stream>>>(Qb, Kb, sK);
        quant_v_old<<<dim3(ND, NBH), blk, 0, stream>>>(Vt, vSc, vZp);
        attn2<<<dim3(NT / 64, NBH), blk, 0, stream>>>(Qb, Kb, Vt, Ab);
        gemm_bt<false, 0><<<gG, blk, 0, stream>>>(Ab, wo, bo, 1.0f, d_out, flag);
    }
}

// Round 5
// 503.225 us; speedup vs baseline: 2.9709x; 1.0667x over previous
//
#include <hip/hip_runtime.h>
#include <hip/hip_bf16.h>

typedef __hip_bfloat16 bf16;
typedef __attribute__((ext_vector_type(4))) short short4v;
typedef __attribute__((ext_vector_type(8))) short short8;
typedef __attribute__((ext_vector_type(4))) float f32x4;

#define NB 4
#define NT 1024
#define NE 2048
#define NH 32
#define ND 64
#define NBH (NB*NH)

__device__ __forceinline__ short bf16bits(float x) {
    bf16 h = __float2bfloat16(x);
    return *reinterpret_cast<short*>(&h);
}
__device__ __forceinline__ float bitsbf16(short s) {
    bf16 h = *reinterpret_cast<bf16*>(&s);
    return __bfloat162float(h);
}

// async global->LDS, 16B per lane; LDS dest = wave-uniform base + lane*16.
__device__ __forceinline__ void gll16(const bf16* g, bf16* l) {
    __builtin_amdgcn_global_load_lds(
        (const __attribute__((address_space(1))) unsigned int*)g,
        (__attribute__((address_space(3))) unsigned int*)l, 16, 0, 0);
}

// Storage-dtype probe (flag=1 -> inputs are fp32). See round-2 notes.
__global__ void detect_dtype(const unsigned short* __restrict__ w, int* __restrict__ flag) {
    int l = threadIdx.x;
    int big = 0;
    for (int i = l; i < 512; i += 64) {
        unsigned e = (w[i] >> 7) & 0xFFu;
        if (e >= 0x88u) big = 1;
    }
    unsigned long long m = __ballot(big != 0);
    if (l == 0) *flag = (m != 0ULL) ? 1 : 0;
}

// One kernel converting hs + 4 weights to bf16. 2048 elems per block.
__global__ __launch_bounds__(256) void conv_all(
    const void* __restrict__ hs, const void* __restrict__ wq, const void* __restrict__ wk,
    const void* __restrict__ wv, const void* __restrict__ wo,
    bf16* __restrict__ dhs, bf16* __restrict__ dwq, bf16* __restrict__ dwk,
    bf16* __restrict__ dwv, bf16* __restrict__ dwo, const int* __restrict__ flagp)
{
    const bool f32 = (*flagp != 0);
    int bid = blockIdx.x;
    const void* src; bf16* dst; size_t blk;
    if (bid < 4096)      { src = hs; dst = dhs; blk = bid; }
    else {
        int r = (bid - 4096) >> 11, o = (bid - 4096) & 2047;
        blk = o;
        src = r == 0 ? wq : (r == 1 ? wk : (r == 2 ? wv : wo));
        dst = r == 0 ? dwq : (r == 1 ? dwk : (r == 2 ? dwv : dwo));
    }
    size_t i = (blk * 256 + threadIdx.x) * 8;
    if (f32) {
        const float* s = (const float*)src + i;
        f32x4 a = *(const f32x4*)s;
        f32x4 b = *(const f32x4*)(s + 4);
        short8 r8;
        r8[0] = bf16bits(a[0]); r8[1] = bf16bits(a[1]);
        r8[2] = bf16bits(a[2]); r8[3] = bf16bits(a[3]);
        r8[4] = bf16bits(b[0]); r8[5] = bf16bits(b[1]);
        r8[6] = bf16bits(b[2]); r8[7] = bf16bits(b[3]);
        *(short8*)(dst + i) = r8;
    } else {
        *(short8*)(dst + i) = *(const short8*)((const bf16*)src + i);
    }
}

// ---------------- fused QKV GEMM: one launch, grid.z in {0=Q,1=K,2=V} ----------------
// Q: (A@Wq^T + bq)*0.125, per-token fake-quant fused, out [B,H,T,D]
// K: A@Wk^T + bk, abs-max col stats via atomics, out [B,H,T,D]
// V: A@Wv^T + bv, min/max col stats via atomics, out [B,H,D,T] (transposed)
__global__ __launch_bounds__(256) void gemm_qkv(
    const bf16* __restrict__ A,
    const bf16* __restrict__ Wq, const bf16* __restrict__ Wk, const bf16* __restrict__ Wv,
    const void* __restrict__ bq, const void* __restrict__ bk, const void* __restrict__ bv,
    bf16* __restrict__ Qb, bf16* __restrict__ Kb, bf16* __restrict__ Vt,
    const int* __restrict__ flagp,
    int* __restrict__ sKb, int* __restrict__ vMx, int* __restrict__ vNg)
{
    const int K = NE, z = blockIdx.z;
    const bf16* W = z == 0 ? Wq : (z == 1 ? Wk : Wv);
    const void* bias = z == 0 ? bq : (z == 1 ? bk : bv);
    const float scale = z == 0 ? 0.125f : 1.0f;

    __shared__ __align__(16) bf16 As[128 * 32];
    __shared__ __align__(16) bf16 Ws[128 * 32];
    int tid = threadIdx.x;
    int w = tid >> 6, l = tid & 63;
    int lr = l & 15, quad = l >> 4;
    int mBase = blockIdx.y * 128, nBase = blockIdx.x * 128;
    int mw = (w >> 1) * 64, nw = (w & 1) * 64;
    f32x4 acc[4][4] = {};

    const bf16* Ag = A + (size_t)(mBase + w * 16 + (l >> 2)) * K + (l & 3) * 8;
    const bf16* Wg = W + (size_t)(nBase + w * 16 + (l >> 2)) * K + (l & 3) * 8;
    bf16* AsW = As + (w * 16) * 32;
    bf16* WsW = Ws + (w * 16) * 32;

    for (int k0 = 0; k0 < K; k0 += 32) {
        gll16(Ag + k0, AsW);
        gll16(Ag + (size_t)64 * K + k0, AsW + 64 * 32);
        gll16(Wg + k0, WsW);
        gll16(Wg + (size_t)64 * K + k0, WsW + 64 * 32);
        __syncthreads();
        short8 af[4], bfr[4];
        #pragma unroll
        for (int i = 0; i < 4; i++)
            af[i] = *(const short8*)(As + (mw + i * 16 + lr) * 32 + quad * 8);
        #pragma unroll
        for (int j = 0; j < 4; j++)
            bfr[j] = *(const short8*)(Ws + (nw + j * 16 + lr) * 32 + quad * 8);
        #pragma unroll
        for (int i = 0; i < 4; i++)
            #pragma unroll
            for (int j = 0; j < 4; j++)
                acc[i][j] = __builtin_amdgcn_mfma_f32_16x16x32_bf16(
                    af[i], bfr[j], acc[i][j], 0, 0, 0);
        __syncthreads();
    }

    const bool f32 = (*flagp != 0);
    float bv4[4];
    #pragma unroll
    for (int j = 0; j < 4; j++) {
        int n = nBase + nw + j * 16 + lr;
        bv4[j] = f32 ? ((const float*)bias)[n] : bitsbf16(((const short*)bias)[n]);
    }
    float colA[4] = {0.f, 0.f, 0.f, 0.f};
    float colB[4] = {0.f, 0.f, 0.f, 0.f};

    #pragma unroll
    for (int i = 0; i < 4; i++) {
        float v[4][4];
        #pragma unroll
        for (int j = 0; j < 4; j++)
            #pragma unroll
            for (int r = 0; r < 4; r++)
                v[j][r] = (acc[i][j][r] + bv4[j]) * scale;

        if (z == 0) {
            // per-token fake-quant over this wave's 64 cols (= one head's d-range)
            #pragma unroll
            for (int r = 0; r < 4; r++) {
                float mx = 0.f, mn = 0.f;
                #pragma unroll
                for (int j = 0; j < 4; j++) { mx = fmaxf(mx, v[j][r]); mn = fminf(mn, v[j][r]); }
                #pragma unroll
                for (int off = 1; off < 16; off <<= 1) {
                    mx = fmaxf(mx, __shfl_xor(mx, off));
                    mn = fminf(mn, __shfl_xor(mn, off));
                }
                float sc = (mx - mn) * (1.f / 255.f);
                if (sc <= 0.f) sc = 1.f;
                float zq = rintf(-mn / sc);
                #pragma unroll
                for (int j = 0; j < 4; j++) {
                    float q = fminf(fmaxf(rintf(v[j][r] / sc) + zq, 0.f), 255.f);
                    v[j][r] = sc * (q - zq);
                }
            }
        } else if (z == 1) {
            #pragma unroll
            for (int j = 0; j < 4; j++)
                #pragma unroll
                for (int r = 0; r < 4; r++)
                    colA[j] = fmaxf(colA[j], fabsf(v[j][r]));
        } else {
            #pragma unroll
            for (int j = 0; j < 4; j++)
                #pragma unroll
                for (int r = 0; r < 4; r++) {
                    colA[j] = fmaxf(colA[j], v[j][r]);
                    colB[j] = fmaxf(colB[j], -v[j][r]);
                }
        }

        #pragma unroll
        for (int j = 0; j < 4; j++) {
            int n = nBase + nw + j * 16 + lr;
            int h = n >> 6, d = n & (ND - 1);
            #pragma unroll
            for (int r = 0; r < 4; r++) {
                int m = mBase + mw + i * 16 + quad * 4 + r;
                int b = m >> 10, t = m & (NT - 1);
                if (z == 0)
                    Qb[(((size_t)(b * NH + h)) * NT + t) * ND + d] = (bf16)v[j][r];
                else if (z == 1)
                    Kb[(((size_t)(b * NH + h)) * NT + t) * ND + d] = (bf16)v[j][r];
                else
                    Vt[(((size_t)(b * NH + h)) * ND + d) * NT + t] = (bf16)v[j][r];
            }
        }
    }

    if (z >= 1) {
        int b = mBase >> 10;
        #pragma unroll
        for (int j = 0; j < 4; j++) {
            float a = colA[j], c = colB[j];
            a = fmaxf(a, __shfl_xor(a, 16)); a = fmaxf(a, __shfl_xor(a, 32));
            if (z == 2) { c = fmaxf(c, __shfl_xor(c, 16)); c = fmaxf(c, __shfl_xor(c, 32)); }
            if (quad == 0) {
                int n = nBase + nw + j * 16 + lr;
                int idx = (b * NH + (n >> 6)) * 64 + (n & 63);
                if (z == 1) atomicMax(sKb + idx, __float_as_int(a));
                else { atomicMax(vMx + idx, __float_as_int(a)); atomicMax(vNg + idx, __float_as_int(c)); }
            }
        }
    }
}

// O-projection GEMM (bf16 A/W), out row-major [M,N] in flag dtype.
__global__ __launch_bounds__(256) void gemm_o(
    const bf16* __restrict__ A, const bf16* __restrict__ W,
    const void* __restrict__ bias, void* __restrict__ out, const int* __restrict__ flagp)
{
    const int K = NE, N = NE;
    __shared__ __align__(16) bf16 As[128 * 32];
    __shared__ __align__(16) bf16 Ws[128 * 32];
    int tid = threadIdx.x;
    int w = tid >> 6, l = tid & 63;
    int lr = l & 15, quad = l >> 4;
    int mBase = blockIdx.y * 128, nBase = blockIdx.x * 128;
    int mw = (w >> 1) * 64, nw = (w & 1) * 64;
    f32x4 acc[4][4] = {};

    const bf16* Ag = A + (size_t)(mBase + w * 16 + (l >> 2)) * K + (l & 3) * 8;
    const bf16* Wg = W + (size_t)(nBase + w * 16 + (l >> 2)) * K + (l & 3) * 8;
    bf16* AsW = As + (w * 16) * 32;
    bf16* WsW = Ws + (w * 16) * 32;

    for (int k0 = 0; k0 < K; k0 += 32) {
        gll16(Ag + k0, AsW);
        gll16(Ag + (size_t)64 * K + k0, AsW + 64 * 32);
        gll16(Wg + k0, WsW);
        gll16(Wg + (size_t)64 * K + k0, WsW + 64 * 32);
        __syncthreads();
        short8 af[4], bfr[4];
        #pragma unroll
        for (int i = 0; i < 4; i++)
            af[i] = *(const short8*)(As + (mw + i * 16 + lr) * 32 + quad * 8);
        #pragma unroll
        for (int j = 0; j < 4; j++)
            bfr[j] = *(const short8*)(Ws + (nw + j * 16 + lr) * 32 + quad * 8);
        #pragma unroll
        for (int i = 0; i < 4; i++)
            #pragma unroll
            for (int j = 0; j < 4; j++)
                acc[i][j] = __builtin_amdgcn_mfma_f32_16x16x32_bf16(
                    af[i], bfr[j], acc[i][j], 0, 0, 0);
        __syncthreads();
    }

    const bool f32 = (*flagp != 0);
    #pragma unroll
    for (int i = 0; i < 4; i++) {
        #pragma unroll
        for (int j = 0; j < 4; j++) {
            int n = nBase + nw + j * 16 + lr;
            float bv = f32 ? ((const float*)bias)[n] : bitsbf16(((const short*)bias)[n]);
            #pragma unroll
            for (int r = 0; r < 4; r++) {
                int m = mBase + mw + i * 16 + quad * 4 + r;
                float vv = acc[i][j][r] + bv;
                if (f32) ((float*)out)[(size_t)m * N + n] = vv;
                else     ((bf16*)out)[(size_t)m * N + n] = (bf16)vv;
            }
        }
    }
}

// Merged: x<256 -> K smooth+per-token quant (x = t-block); else V per-channel quant (x-256 = d-block).
__global__ __launch_bounds__(256) void quant_kv(
    bf16* __restrict__ Kb, bf16* __restrict__ Vt,
    const int* __restrict__ sKbits, const int* __restrict__ vMax, const int* __restrict__ vNeg)
{
    int bh = blockIdx.y;
    if (blockIdx.x < 256) {
        int t = blockIdx.x * 4 + (threadIdx.x >> 6);
        int l = threadIdx.x & 63;
        size_t idx = ((size_t)bh * NT + t) * ND + l;
        float s = fmaxf(__int_as_float(sKbits[bh * 64 + l]), 1e-5f);
        float x = (float)Kb[idx] / s;
        float mx = fmaxf(x, 0.f), mn = fminf(x, 0.f);
        #pragma unroll
        for (int off = 1; off < 64; off <<= 1) {
            mx = fmaxf(mx, __shfl_xor(mx, off));
            mn = fminf(mn, __shfl_xor(mn, off));
        }
        float sc = (mx - mn) * (1.f / 255.f);
        if (sc <= 0.f) sc = 1.f;
        float z = rintf(-mn / sc);
        float q = fminf(fmaxf(rintf(x / sc) + z, 0.f), 255.f);
        Kb[idx] = (bf16)(s * (sc * (q - z)));
    } else {
        int d = (blockIdx.x - 256) * 8 + (threadIdx.x >> 5);
        int c = (threadIdx.x & 31) * 8;
        float mx = __int_as_float(vMax[bh * 64 + d]);
        float mn = -__int_as_float(vNeg[bh * 64 + d]);
        float sc = (mx - mn) * (1.f / 255.f);
        if (sc <= 0.f) sc = 1.f;
        float z = rintf(-mn / sc);
        bf16* row = Vt + ((size_t)bh * ND + d) * NT;
        for (int seg = 0; seg < 4; seg++) {
            int off = seg * 256 + c;
            short8 v8 = *(const short8*)(row + off);
            #pragma unroll
            for (int k = 0; k < 8; k++) {
                float f = bitsbf16(v8[k]);
                float q = fminf(fmaxf(rintf(f / sc) + z, 0.f), 255.f);
                v8[k] = bf16bits(sc * (q - z));
            }
            *(short8*)(row + off) = v8;
        }
    }
}

// Flash-style causal attention, double-buffered XOR-SWIZZLED LDS K/V staging.
// LDS tile layout: LDS[row][slot] = global[row][colblk = slot ^ (row&7)], colblk = 8 elems (16B).
// Fragment read of global colblk g for row R -> LDS slot g ^ (R&7): spreads b128 reads
// over all 32 banks (8-cyc floor instead of 16).
__global__ __launch_bounds__(256) void attn3(
    const bf16* __restrict__ Q, const bf16* __restrict__ K,
    const bf16* __restrict__ Vt, bf16* __restrict__ O)
{
    int bh = blockIdx.y;
    int b = bh >> 5, h = bh & 31;
    int qb = (int)gridDim.x - 1 - (int)blockIdx.x;   // heavy blocks first
    int qBase = qb * 64;
    int w = threadIdx.x >> 6, l = threadIdx.x & 63;
    int lr = l & 15, quad = l >> 4;
    int qRow = qBase + w * 16;

    __shared__ __align__(16) bf16 Ks[2][64 * 64];
    __shared__ __align__(16) bf16 Vs[2][64 * 64];
    __shared__ __align__(16) bf16 Psh[4][16 * 64];

    const bf16* Kbase = K + (size_t)bh * NT * ND;
    const bf16* Vbase = Vt + (size_t)bh * ND * NT;

    const bf16* Qp = Q + ((size_t)bh * NT + qRow + lr) * ND + quad * 8;
    short8 qf0 = *(const short8*)Qp;
    short8 qf1 = *(const short8*)(Qp + 32);

    f32x4 o[4] = {};
    float m_i[4], l_i[4];
    #pragma unroll
    for (int r = 0; r < 4; r++) { m_i[r] = -1e30f; l_i[r] = 0.f; }

    int nkt = qb + 1;
    int srow = w * 16 + (l >> 3);                    // within-tile row
    int scol = (((l & 7) ^ ((l >> 3) & 7))) * 8;     // swizzled source colblk

    auto stage = [&](int kt, int bufi) {
        int kc0 = kt * 64;
        #pragma unroll
        for (int c = 0; c < 2; c++) {
            gll16(Kbase + (size_t)(kc0 + srow + c * 8) * ND + scol,
                  &Ks[bufi][(w * 16 + c * 8) * 64]);
            gll16(Vbase + (size_t)(srow + c * 8) * NT + kc0 + scol,
                  &Vs[bufi][(w * 16 + c * 8) * 64]);
        }
    };
    stage(0, 0);

    int slot0 = (quad ^ (lr & 7)) * 8;               // swizzled slot for colblk quad
    int slot1 = ((quad ^ 4) ^ (lr & 7)) * 8;         // colblk 4+quad

    for (int kt = 0; kt < nkt; kt++) {
        __syncthreads();               // buf[kt&1] staged; prev-iter LDS reads done
        if (kt + 1 < nkt) stage(kt + 1, (kt + 1) & 1);
        const bf16* Kt = Ks[kt & 1];
        const bf16* Vv = Vs[kt & 1];
        int kc0 = kt * 64;

        f32x4 s[4] = {};
        #pragma unroll
        for (int nb = 0; nb < 4; nb++) {
            short8 b0 = *(const short8*)(Kt + (nb * 16 + lr) * 64 + slot0);
            short8 b1 = *(const short8*)(Kt + (nb * 16 + lr) * 64 + slot1);
            s[nb] = __builtin_amdgcn_mfma_f32_16x16x32_bf16(qf0, b0, s[nb], 0, 0, 0);
            s[nb] = __builtin_amdgcn_mfma_f32_16x16x32_bf16(qf1, b1, s[nb], 0, 0, 0);
        }

        int row0 = qRow + quad * 4;
        float rmax[4];
        #pragma unroll
        for (int r = 0; r < 4; r++) rmax[r] = -1e30f;
        if (kt == qb) {                // only the diagonal tile needs masking
            #pragma unroll
            for (int nb = 0; nb < 4; nb++) {
                int col = kc0 + nb * 16 + lr;
                #pragma unroll
                for (int r = 0; r < 4; r++) {
                    if (col > row0 + r) s[nb][r] = -1e30f;
                    rmax[r] = fmaxf(rmax[r], s[nb][r]);
                }
            }
        } else {
            #pragma unroll
            for (int nb = 0; nb < 4; nb++)
                #pragma unroll
                for (int r = 0; r < 4; r++)
                    rmax[r] = fmaxf(rmax[r], s[nb][r]);
        }
        #pragma unroll
        for (int off = 1; off < 16; off <<= 1)
            #pragma unroll
            for (int r = 0; r < 4; r++)
                rmax[r] = fmaxf(rmax[r], __shfl_xor(rmax[r], off));

        float alpha[4], rsum[4];
        #pragma unroll
        for (int r = 0; r < 4; r++) {
            float mn2 = fmaxf(m_i[r], rmax[r]);
            alpha[r] = __expf(m_i[r] - mn2);
            m_i[r] = mn2;
            rsum[r] = 0.f;
        }
        // write P swizzled: row=quad*4+r, col=nb*16+lr -> cb = nb*2+(lr>>3), ci = lr&7
        #pragma unroll
        for (int nb = 0; nb < 4; nb++) {
            int cb = nb * 2 + (lr >> 3), ci = lr & 7;
            #pragma unroll
            for (int r = 0; r < 4; r++) {
                float pp = __expf(s[nb][r] - m_i[r]);
                rsum[r] += pp;
                int row = quad * 4 + r;
                Psh[w][row * 64 + (cb ^ (row & 7)) * 8 + ci] = (bf16)pp;
            }
        }
        #pragma unroll
        for (int off = 1; off < 16; off <<= 1)
            #pragma unroll
            for (int r = 0; r < 4; r++)
                rsum[r] += __shfl_xor(rsum[r], off);
        #pragma unroll
        for (int r = 0; r < 4; r++) l_i[r] = l_i[r] * alpha[r] + rsum[r];
        #pragma unroll
        for (int f = 0; f < 4; f++)
            #pragma unroll
            for (int r = 0; r < 4; r++)
                o[f][r] *= alpha[r];

        __syncthreads();               // Psh visible
        short8 p0 = *(const short8*)(&Psh[w][lr * 64 + slot0]);
        short8 p1 = *(const short8*)(&Psh[w][lr * 64 + slot1]);
        #pragma unroll
        for (int f = 0; f < 4; f++) {
            short8 v0 = *(const short8*)(Vv + (f * 16 + lr) * 64 + slot0);
            short8 v1 = *(const short8*)(Vv + (f * 16 + lr) * 64 + slot1);
            o[f] = __builtin_amdgcn_mfma_f32_16x16x32_bf16(p0, v0, o[f], 0, 0, 0);
            o[f] = __builtin_amdgcn_mfma_f32_16x16x32_bf16(p1, v1, o[f], 0, 0, 0);
        }
    }

    float inv[4];
    #pragma unroll
    for (int r = 0; r < 4; r++) inv[r] = 1.f / l_i[r];
    #pragma unroll
    for (int f = 0; f < 4; f++)
        #pragma unroll
        for (int r = 0; r < 4; r++) {
            int t = qRow + quad * 4 + r;
            int d = f * 16 + lr;
            O[((size_t)(b * NT + t)) * NE + h * ND + d] = (bf16)(o[f][r] * inv[r]);
        }
}

// ---------------- fallback path (round-3, validated; used if ws too small) ----------------
__device__ __forceinline__ void stage_tile(const void* __restrict__ src, bool f32,
                                           int rowBase, int k0, bf16* dst, int tid)
{
    const int K = NE;
    if (f32) {
        int r = tid >> 3;
        int c = (tid & 7) * 4;
        const float* p = (const float*)src + (size_t)(rowBase + r) * K + k0 + c;
        bf16* d = dst + r * 32 + c;
        #pragma unroll
        for (int i = 0; i < 4; i++) {
            f32x4 v = *(const f32x4*)(p + (size_t)(i * 32) * K);
            short4v o;
            o[0] = bf16bits(v[0]); o[1] = bf16bits(v[1]);
            o[2] = bf16bits(v[2]); o[3] = bf16bits(v[3]);
            *(short4v*)(d + i * 32 * 32) = o;
        }
    } else {
        int r = tid >> 2;
        int c = (tid & 3) * 8;
        const bf16* p = (const bf16*)src + (size_t)(rowBase + r) * K + k0 + c;
        bf16* d = dst + r * 32 + c;
        #pragma unroll
        for (int i = 0; i < 2; i++)
            *(short8*)(d + i * 64 * 32) = *(const short8*)(p + (size_t)(i * 64) * K);
    }
}

template<bool A_DYN, int MODE>
__global__ __launch_bounds__(256) void gemm_bt(
    const void* __restrict__ A, const void* __restrict__ W,
    const void* __restrict__ bias, float scale, void* __restrict__ out,
    const int* __restrict__ flagp)
{
    const int K = NE, N = NE;
    const bool f32 = (*flagp != 0);
    __shared__ __align__(16) bf16 As[128 * 32];
    __shared__ __align__(16) bf16 Ws[128 * 32];
    int tid = threadIdx.x;
    int w = tid >> 6, l = tid & 63;
    int lr = l & 15, quad = l >> 4;
    int mBase = blockIdx.y * 128;
    int nBase = blockIdx.x * 128;
    int mw = (w >> 1) * 64, nw = (w & 1) * 64;
    f32x4 acc[4][4] = {};
    for (int k0 = 0; k0 < K; k0 += 32) {
        stage_tile(A, A_DYN && f32, mBase, k0, As, tid);
        stage_tile(W, f32, nBase, k0, Ws, tid);
        __syncthreads();
        short8 af[4], bfr[4];
        #pragma unroll
        for (int i = 0; i < 4; i++)
            af[i] = *(const short8*)(As + (mw + i * 16 + lr) * 32 + quad * 8);
        #pragma unroll
        for (int j = 0; j < 4; j++)
            bfr[j] = *(const short8*)(Ws + (nw + j * 16 + lr) * 32 + quad * 8);
        #pragma unroll
        for (int i = 0; i < 4; i++)
            #pragma unroll
            for (int j = 0; j < 4; j++)
                acc[i][j] = __builtin_amdgcn_mfma_f32_16x16x32_bf16(
                    af[i], bfr[j], acc[i][j], 0, 0, 0);
        __syncthreads();
    }
    #pragma unroll
    for (int i = 0; i < 4; i++) {
        #pragma unroll
        for (int j = 0; j < 4; j++) {
            int n = nBase + nw + j * 16 + lr;
            float bv = f32 ? ((const float*)bias)[n] : bitsbf16(((const short*)bias)[n]);
            #pragma unroll
            for (int r = 0; r < 4; r++) {
                int m = mBase + mw + i * 16 + quad * 4 + r;
                float v = (acc[i][j][r] + bv) * scale;
                if (MODE == 0) {
                    if (f32) ((float*)out)[(size_t)m * N + n] = v;
                    else     ((bf16*)out)[(size_t)m * N + n] = (bf16)v;
                } else {
                    int b = m >> 10, t = m & (NT - 1);
                    int h = n >> 6, d = n & (ND - 1);
                    if (MODE == 1)
                        ((bf16*)out)[(((size_t)(b * NH + h)) * NT + t) * ND + d] = (bf16)v;
                    else
                        ((bf16*)out)[(((size_t)(b * NH + h)) * ND + d) * NT + t] = (bf16)v;
                }
            }
        }
    }
}

__global__ __launch_bounds__(256) void stats_k(
    const bf16* __restrict__ K, float* __restrict__ sK)
{
    int bh = blockIdx.x;
    int d = threadIdx.x & 63, tg = threadIdx.x >> 6;
    const bf16* Kp = K + (size_t)bh * NT * ND;
    float kabs = 0.f;
    for (int t = tg; t < NT; t += 4)
        kabs = fmaxf(kabs, fabsf((float)Kp[t * ND + d]));
    __shared__ float sh[4][64];
    sh[tg][d] = kabs;
    __syncthreads();
    if (threadIdx.x < 64) {
        kabs = fmaxf(fmaxf(sh[0][d], sh[1][d]), fmaxf(sh[2][d], sh[3][d]));
        sK[bh * 64 + d] = fmaxf(kabs, 1e-5f);
    }
}

__global__ __launch_bounds__(256) void stats_v(
    const bf16* __restrict__ Vt, float* __restrict__ vScale, float* __restrict__ vZero)
{
    int bh = blockIdx.x;
    int c = threadIdx.x >> 2;
    int seg = threadIdx.x & 3;
    const bf16* row = Vt + ((size_t)bh * ND + c) * NT + seg * 256;
    float vmax = 0.f, vmin = 0.f;
    for (int i = 0; i < 256; i += 8) {
        short8 v8 = *(const short8*)(row + i);
        for (int j = 0; j < 8; j++) {
            float f = bitsbf16(v8[j]);
            vmax = fmaxf(vmax, f);
            vmin = fminf(vmin, f);
        }
    }
    vmax = fmaxf(vmax, __shfl_xor(vmax, 1));
    vmax = fmaxf(vmax, __shfl_xor(vmax, 2));
    vmin = fminf(vmin, __shfl_xor(vmin, 1));
    vmin = fminf(vmin, __shfl_xor(vmin, 2));
    if (seg == 0) {
        float sc = (vmax - vmin) * (1.f / 255.f);
        if (sc <= 0.f) sc = 1.f;
        vScale[bh * 64 + c] = sc;
        vZero[bh * 64 + c] = rintf(-vmin / sc);
    }
}

__global__ __launch_bounds__(256) void quant_qk(
    bf16* __restrict__ Q, bf16* __restrict__ K, const float* __restrict__ sK)
{
    int bh = blockIdx.y;
    int t = blockIdx.x * 4 + (threadIdx.x >> 6);
    int l = threadIdx.x & 63;
    size_t idx = ((size_t)bh * NT + t) * ND + l;
    {
        float x = (float)Q[idx];
        float xmax = fmaxf(x, 0.f), xmin = fminf(x, 0.f);
        for (int off = 1; off < 64; off <<= 1) {
            xmax = fmaxf(xmax, __shfl_xor(xmax, off));
            xmin = fminf(xmin, __shfl_xor(xmin, off));
        }
        float sc = (xmax - xmin) * (1.f / 255.f);
        if (sc <= 0.f) sc = 1.f;
        float z = rintf(-xmin / sc);
        float q = fminf(fmaxf(rintf(x / sc) + z, 0.f), 255.f);
        Q[idx] = (bf16)(sc * (q - z));
    }
    {
        float s = sK[bh * 64 + l];
        float x = (float)K[idx] / s;
        float xmax = fmaxf(x, 0.f), xmin = fminf(x, 0.f);
        for (int off = 1; off < 64; off <<= 1) {
            xmax = fmaxf(xmax, __shfl_xor(xmax, off));
            xmin = fminf(xmin, __shfl_xor(xmin, off));
        }
        float sc = (xmax - xmin) * (1.f / 255.f);
        if (sc <= 0.f) sc = 1.f;
        float z = rintf(-xmin / sc);
        float q = fminf(fmaxf(rintf(x / sc) + z, 0.f), 255.f);
        K[idx] = (bf16)(s * (sc * (q - z)));
    }
}

__global__ __launch_bounds__(256) void quant_v_old(
    bf16* __restrict__ Vt,
    const float* __restrict__ vScale, const float* __restrict__ vZero)
{
    int bh = blockIdx.y, d = blockIdx.x;
    float sc = vScale[bh * 64 + d], z = vZero[bh * 64 + d];
    bf16* row = Vt + ((size_t)bh * ND + d) * NT;
    for (int t = threadIdx.x; t < NT; t += 256) {
        float v = (float)row[t];
        float q = fminf(fmaxf(rintf(v / sc) + z, 0.f), 255.f);
        row[t] = (bf16)(sc * (q - z));
    }
}

extern "C" void kernel_launch(void* const* d_in, const int* in_sizes, int n_in,
                              void* d_out, int out_size, void* d_ws, size_t ws_size,
                              hipStream_t stream)
{
    (void)in_sizes; (void)n_in; (void)out_size;
    const void* hs = d_in[0];
    const void* wq = d_in[1];
    const void* bq = d_in[2];
    const void* wk = d_in[3];
    const void* bk = d_in[4];
    const void* wv = d_in[5];
    const void* bv = d_in[6];
    const void* wo = d_in[7];
    const void* bo = d_in[8];
    // d_in[9] = attention_mask: exact causal, applied analytically.

    const size_t qkvE = (size_t)NBH * NT * ND;       // 8.39M elems
    const size_t qkvB = qkvE * 2;                    // 16.78 MB
    const size_t wBy  = (size_t)NE * NE * 2;         // 8.39 MB
    const size_t statB = 3 * (size_t)NBH * ND * 4;   // 96 KB
    const size_t needFast = 4 * qkvB + 4 * wBy + statB + 256;

    dim3 blk(256);
    dim3 gG(NE / 128, (NB * NT) / 128);
    const float scaling = 0.125f;  // 64^-0.5

    if (ws_size >= needFast) {
        char* p = (char*)d_ws;
        bf16* Qb  = (bf16*)p; p += qkvB;
        bf16* Kb  = (bf16*)p; p += qkvB;
        bf16* Vt  = (bf16*)p; p += qkvB;
        bf16* hsB = (bf16*)p; p += qkvB;             // reused as Ab after QKV
        bf16* wqB = (bf16*)p; p += wBy;
        bf16* wkB = (bf16*)p; p += wBy;
        bf16* wvB = (bf16*)p; p += wBy;
        bf16* woB = (bf16*)p; p += wBy;
        int* sKb = (int*)p;
        int* vMx = sKb + NBH * ND;
        int* vNg = vMx + NBH * ND;
        int* flag = vNg + NBH * ND;
        bf16* Ab = hsB;

        detect_dtype<<<dim3(1), dim3(64), 0, stream>>>((const unsigned short*)wq, flag);
        hipMemsetAsync(sKb, 0, statB, stream);
        conv_all<<<dim3(4096 + 4 * 2048), blk, 0, stream>>>(
            hs, wq, wk, wv, wo, hsB, wqB, wkB, wvB, woB, flag);
        gemm_qkv<<<dim3(NE / 128, (NB * NT) / 128, 3), blk, 0, stream>>>(
            hsB, wqB, wkB, wvB, bq, bk, bv, Qb, Kb, Vt, flag, sKb, vMx, vNg);
        quant_kv<<<dim3(256 + ND / 8, NBH), blk, 0, stream>>>(Kb, Vt, sKb, vMx, vNg);
        attn3<<<dim3(NT / 64, NBH), blk, 0, stream>>>(Qb, Kb, Vt, Ab);
        gemm_o<<<gG, blk, 0, stream>>>(Ab, woB, bo, d_out, flag);
    } else {
        bf16* Qb = (bf16*)d_ws;
        bf16* Kb = Qb + qkvE;
        bf16* Vt = Kb + qkvE;
        bf16* Ab = Vt + qkvE;
        float* sK  = (float*)(Ab + qkvE);
        float* vSc = sK + NBH * ND;
        float* vZp = vSc + NBH * ND;
        int*   flag = (int*)(vZp + NBH * ND);

        detect_dtype<<<dim3(1), dim3(64), 0, stream>>>((const unsigned short*)wq, flag);
        gemm_bt<true, 1><<<gG, blk, 0, stream>>>(hs, wq, bq, scaling, Qb, flag);
        gemm_bt<true, 1><<<gG, blk, 0, stream>>>(hs, wk, bk, 1.0f, Kb, flag);
        gemm_bt<true, 2><<<gG, blk, 0, stream>>>(hs, wv, bv, 1.0f, Vt, flag);
        stats_k<<<dim3(NBH), blk, 0, stream>>>(Kb, sK);
        stats_v<<<dim3(NBH), blk, 0, stream>>>(Vt, vSc, vZp);
        quant_qk<<<dim3(NT / 4, NBH), blk, 0, stream>>>(Qb, Kb, sK);
        quant_v_old<<<dim3(ND, NBH), blk, 0, stream>>>(Vt, vSc, vZp);
        attn3<<<dim3(NT / 64, NBH), blk, 0, stream>>>(Qb, Kb, Vt, Ab);
        gemm_bt<false, 0><<<gG, blk, 0, stream>>>(Ab, wo, bo, 1.0f, d_out, flag);
    }
}